// Round 16
// baseline (1252.222 us; speedup 1.0000x reference)
//
#include <hip/hip_runtime.h>
#include <math.h>

#define N_LAYERS 4
#define DMODEL 1024
#define DINNER 2048
#define DSTATE 16
#define DTRANK 64
#define DCONV 4
#define NBATCH 2
#define LSEQ 2048
#define LNEPS 1e-5f
#define ROWS (NBATCH * LSEQ)   // 4096
#define CLEN 32
#define NCHUNK (LSEQ / CLEN)   // 64
#define XP 128                 // padded x_proj output pitch (dt 0:64, B 64:80, C 80:96)
#define KSLICE 256             // x_proj split-K slice
#define NSLICE (DINNER / KSLICE)  // 8
#define OPSLICE 2              // out_proj split-K slices

typedef __attribute__((ext_vector_type(8))) short bf16x8;
typedef __attribute__((ext_vector_type(8))) unsigned short ushort8;
typedef __attribute__((ext_vector_type(4))) float f32x4;
typedef __attribute__((ext_vector_type(4))) unsigned int uint4v;

__device__ __forceinline__ unsigned short f2bf(float f) {
  unsigned int u = __float_as_uint(f);
  return (unsigned short)((u + 0x7FFFu + ((u >> 16) & 1u)) >> 16);  // RNE
}
__device__ __forceinline__ float bf2f(unsigned short h) {
  return __uint_as_float(((unsigned int)h) << 16);
}

__device__ __forceinline__ void gload16(const unsigned short* g, unsigned short* l) {
  __builtin_amdgcn_global_load_lds(
      (const __attribute__((address_space(1))) unsigned int*)g,
      (__attribute__((address_space(3))) unsigned int*)l, 16, 0, 0);
}

// fast softplus via HW v_exp/v_log (R7: libm version cost 100 us/layer)
__device__ __forceinline__ float softplus_f(float x) {
  float e = __expf(-fabsf(x));
  return fmaxf(x, 0.f) + __logf(1.f + e);
}

// ---------------- fp32 -> bf16 weight conversion -----------------------------
__global__ __launch_bounds__(256) void cvt_f2bf(const float* __restrict__ src,
                                                unsigned short* __restrict__ dst, int n4) {
  int i = blockIdx.x * 256 + threadIdx.x;
  if (i >= n4) return;
  float4 v = ((const float4*)src)[i];
  ushort4 o;
  o.x = f2bf(v.x); o.y = f2bf(v.y); o.z = f2bf(v.z); o.w = f2bf(v.w);
  ((ushort4*)dst)[i] = o;
}

// x_proj_w [4][96][2048] -> padded bf16 [4][128][2048] (rows 96..127 zero)
__global__ __launch_bounds__(256) void cvt_xpw(const float* __restrict__ src,
                                               unsigned short* __restrict__ dst) {
  int i = blockIdx.x * 256 + threadIdx.x;    // over 4*128*512
  int col4 = i & 511;
  int row = (i >> 9) & 127;
  int layer = i >> 16;
  float4 v = make_float4(0.f, 0.f, 0.f, 0.f);
  if (row < 96) v = ((const float4*)(src + ((size_t)layer * 96 + row) * 2048))[col4];
  ushort4 o;
  o.x = f2bf(v.x); o.y = f2bf(v.y); o.z = f2bf(v.z); o.w = f2bf(v.w);
  ((ushort4*)(dst + ((size_t)layer * 128 + row) * 2048))[col4] = o;
}

// ---------------- LayerNorm: fp32 in, bf16 (hidden path) or fp32 (final) out -
template<bool OBF>
__global__ __launch_bounds__(256) void ln_kernel(
    const float* __restrict__ src, float* __restrict__ res_copy,
    const float* __restrict__ w, const float* __restrict__ b, void* out) {
  int row = blockIdx.x;
  int t = threadIdx.x;
  const float4* srow = (const float4*)(src + (size_t)row * DMODEL);
  float4 v = srow[t];
  if (res_copy) ((float4*)(res_copy + (size_t)row * DMODEL))[t] = v;
  float s = v.x + v.y + v.z + v.w;
  float sq = v.x * v.x + v.y * v.y + v.z * v.z + v.w * v.w;
  #pragma unroll
  for (int o = 32; o >= 1; o >>= 1) {
    s += __shfl_xor(s, o);
    sq += __shfl_xor(sq, o);
  }
  __shared__ float ss[4], ssq[4];
  int wid = t >> 6, lane = t & 63;
  if (lane == 0) { ss[wid] = s; ssq[wid] = sq; }
  __syncthreads();
  s = ss[0] + ss[1] + ss[2] + ss[3];
  sq = ssq[0] + ssq[1] + ssq[2] + ssq[3];
  float mu = s * (1.f / DMODEL);
  float var = sq * (1.f / DMODEL) - mu * mu;
  float rs = rsqrtf(var + LNEPS);
  float4 wv = ((const float4*)w)[t];
  float4 bv = ((const float4*)b)[t];
  float4 o4;
  o4.x = (v.x - mu) * rs * wv.x + bv.x;
  o4.y = (v.y - mu) * rs * wv.y + bv.y;
  o4.z = (v.z - mu) * rs * wv.z + bv.z;
  o4.w = (v.w - mu) * rs * wv.w + bv.w;
  if (OBF) {
    ushort4 ob;
    ob.x = f2bf(o4.x); ob.y = f2bf(o4.y); ob.z = f2bf(o4.z); ob.w = f2bf(o4.w);
    ((ushort4*)((unsigned short*)out + (size_t)row * DMODEL))[t] = ob;
  } else {
    ((float4*)((float*)out + (size_t)row * DMODEL))[t] = o4;
  }
}

// ==== 256x256 bf16 MFMA GEMM, reg-staged + padded LDS, 2-deep prefetch =======
// R15 post-mortem: 1-deep reg prefetch left global latency exposed (loads had
// <1 tile-time to land). Two reg sets: loads for tile t+2 issue at iter t,
// consumed by dswrite at end of iter t+1 -> each load gets a full tile-time.
// The vmcnt wait in dswrite only drains the OLDER set (counted, never 0).
template<int ACT, bool BIAS, bool ADD, bool WF32, bool WBF>
__global__ __launch_bounds__(512) void gemm256r(
    const unsigned short* __restrict__ A, int lda,
    const unsigned short* __restrict__ W, int ldw,
    float* __restrict__ C, int ldc, int K,
    const float* __restrict__ bias,
    const float* __restrict__ addsrc,
    unsigned short* __restrict__ Cb) {
  __shared__ unsigned short lds[2][256][72];   // 72 KB, +16B/row pad
  const int t = threadIdx.x;
  const int lane = t & 63;
  const int wave = t >> 6;
  const int wr = wave >> 2;          // 0..1 (M half)
  const int wc = wave & 3;           // 0..3 (N quarter)
  const int m0 = blockIdx.y * 256, n0 = blockIdx.x * 256;
  const int frow = lane & 15;
  const int hi = lane >> 4;

  const int srow = t >> 3;           // staging row base 0..63 (+64*r)
  const int sc8 = (t & 7) << 3;      // staging chunk col (elements)

  f32x4 acc[8][4];
  #pragma unroll
  for (int m = 0; m < 8; m++)
    #pragma unroll
    for (int n = 0; n < 4; n++) acc[m][n] = (f32x4){0.f, 0.f, 0.f, 0.f};

  const int NT = K / 64;             // in_proj: 16 (even, required by 2-unroll)
  ushort8 aregA[4], wregA[4], aregB[4], wregB[4];

  auto loadA = [&](int kt) {
    #pragma unroll
    for (int r = 0; r < 4; ++r) {
      int row = srow + (r << 6);
      aregA[r] = *(const ushort8*)(A + (size_t)(m0 + row) * lda + kt * 64 + sc8);
      wregA[r] = *(const ushort8*)(W + (size_t)(n0 + row) * ldw + kt * 64 + sc8);
    }
  };
  auto loadB = [&](int kt) {
    #pragma unroll
    for (int r = 0; r < 4; ++r) {
      int row = srow + (r << 6);
      aregB[r] = *(const ushort8*)(A + (size_t)(m0 + row) * lda + kt * 64 + sc8);
      wregB[r] = *(const ushort8*)(W + (size_t)(n0 + row) * ldw + kt * 64 + sc8);
    }
  };
  auto dswriteA = [&]() {
    #pragma unroll
    for (int r = 0; r < 4; ++r) {
      int row = srow + (r << 6);
      *(ushort8*)&lds[0][row][sc8] = aregA[r];
      *(ushort8*)&lds[1][row][sc8] = wregA[r];
    }
  };
  auto dswriteB = [&]() {
    #pragma unroll
    for (int r = 0; r < 4; ++r) {
      int row = srow + (r << 6);
      *(ushort8*)&lds[0][row][sc8] = aregB[r];
      *(ushort8*)&lds[1][row][sc8] = wregB[r];
    }
  };
  auto compute = [&]() {
    #pragma unroll
    for (int ks = 0; ks < 2; ++ks) {
      bf16x8 a[8], b[4];
      #pragma unroll
      for (int m = 0; m < 8; ++m)
        a[m] = *(const bf16x8*)&lds[0][wr * 128 + m * 16 + frow][(ks * 4 + hi) << 3];
      #pragma unroll
      for (int n = 0; n < 4; ++n)
        b[n] = *(const bf16x8*)&lds[1][wc * 64 + n * 16 + frow][(ks * 4 + hi) << 3];
      __builtin_amdgcn_s_setprio(1);
      #pragma unroll
      for (int m = 0; m < 8; ++m)
        #pragma unroll
        for (int n = 0; n < 4; ++n)
          acc[m][n] = __builtin_amdgcn_mfma_f32_16x16x32_bf16(a[m], b[n], acc[m][n], 0, 0, 0);
      __builtin_amdgcn_s_setprio(0);
    }
  };

  // prologue: tile0 -> A set -> LDS; tile1 -> B set (in flight)
  loadA(0);
  loadB(1);
  dswriteA();                  // waits only A's loads (B issued after -> counted)
  __syncthreads();
  for (int kt = 0; kt < NT; kt += 2) {
    // even tile kt (LDS holds it); A set is free
    if (kt + 2 < NT) loadA(kt + 2);
    compute();
    __syncthreads();
    if (kt + 1 < NT) { dswriteB(); __syncthreads(); }
    // odd tile kt+1; B set is free
    if (kt + 3 < NT) loadB(kt + 3);
    compute();
    __syncthreads();
    if (kt + 2 < NT) { dswriteA(); __syncthreads(); }
  }

  #pragma unroll
  for (int m = 0; m < 8; ++m) {
    int rbase = m0 + wr * 128 + m * 16 + hi * 4;
    #pragma unroll
    for (int n = 0; n < 4; ++n) {
      int ccol = n0 + wc * 64 + n * 16 + frow;
      #pragma unroll
      for (int j = 0; j < 4; ++j) {
        int crow = rbase + j;
        float v = acc[m][n][j];
        if (BIAS) v += bias[ccol];
        if (ACT == 1) v = softplus_f(v);
        if (ADD) v += addsrc[(size_t)crow * ldc + ccol];
        if (WF32) C[(size_t)crow * ldc + ccol] = v;
        if (WBF) Cb[(size_t)crow * ldc + ccol] = f2bf(v);
      }
    }
  }
}

// ------------- 128x128 2-phase GEMM (R12-proven; dt/x/out_proj) --------------
template<int ACT, bool BIAS, bool ADD, bool WF32, bool WBF, bool PARTIAL>
__global__ __launch_bounds__(256) void gemm_bf16(
    const unsigned short* __restrict__ A, int lda,
    const unsigned short* __restrict__ W, int ldw,
    float* __restrict__ C, int ldc, int K,
    const float* __restrict__ bias,
    const float* __restrict__ addsrc,
    unsigned short* __restrict__ Cb) {
  __shared__ unsigned short As[2][128][32];
  __shared__ unsigned short Ws[2][128][32];
  int t = threadIdx.x;
  int lane = t & 63, wave = t >> 6;
  int wr = wave >> 1, wc = wave & 1;
  int m0 = blockIdx.y * 128, n0 = blockIdx.x * 128;

  int kbase = 0;
  if (PARTIAL) {
    kbase = blockIdx.z * K;
    C += (size_t)blockIdx.z * (size_t)gridDim.y * 128 * ldc;
  }

  int r0 = t >> 2;
  int kk8 = (t & 3) << 3;
  const unsigned short* Ag = A + (size_t)(m0 + r0) * lda + kbase + kk8;
  const unsigned short* Wg = W + (size_t)(n0 + r0) * ldw + kbase + kk8;
  const size_t Astep = (size_t)64 * lda;
  const size_t Wstep = (size_t)64 * ldw;

  f32x4 zero = {0.f, 0.f, 0.f, 0.f};
  f32x4 acc[4][4];
  #pragma unroll
  for (int m = 0; m < 4; m++)
    #pragma unroll
    for (int n = 0; n < 4; n++) acc[m][n] = zero;

  int frow = lane & 15;
  int fk = (lane >> 4) << 3;

  auto stage = [&](int buf, int kt) {
    const unsigned short* ag = Ag + kt * 32;
    const unsigned short* wg = Wg + kt * 32;
    unsigned short* la = &As[buf][r0][kk8];
    unsigned short* lw = &Ws[buf][r0][kk8];
    gload16(ag, la);
    gload16(ag + Astep, la + 64 * 32);
    gload16(wg, lw);
    gload16(wg + Wstep, lw + 64 * 32);
  };
  auto compute = [&](int buf) {
    bf16x8 af[4], bw[4];
    #pragma unroll
    for (int m = 0; m < 4; m++)
      af[m] = *(const bf16x8*)&As[buf][wr * 64 + m * 16 + frow][fk];
    #pragma unroll
    for (int n = 0; n < 4; n++)
      bw[n] = *(const bf16x8*)&Ws[buf][wc * 64 + n * 16 + frow][fk];
    #pragma unroll
    for (int m = 0; m < 4; m++)
      #pragma unroll
      for (int n = 0; n < 4; n++)
        acc[m][n] = __builtin_amdgcn_mfma_f32_16x16x32_bf16(af[m], bw[n], acc[m][n], 0, 0, 0);
  };

  const int NT = K / 32;
  stage(0, 0);
  __syncthreads();
  int cur = 0;
  for (int kt = 0; kt < NT - 1; ++kt) {
    stage(cur ^ 1, kt + 1);
    compute(cur);
    __syncthreads();
    cur ^= 1;
  }
  compute(cur);

  #pragma unroll
  for (int m = 0; m < 4; m++) {
    int rbase = m0 + wr * 64 + m * 16 + ((lane >> 4) << 2);
    #pragma unroll
    for (int n = 0; n < 4; n++) {
      int ccol = n0 + wc * 64 + n * 16 + (lane & 15);
      #pragma unroll
      for (int j = 0; j < 4; j++) {
        int crow = rbase + j;
        float v = acc[m][n][j];
        if (BIAS) v += bias[ccol];
        if (ACT == 1) v = softplus_f(v);
        if (ADD) v += addsrc[(size_t)crow * ldc + ccol];
        if (WF32 || PARTIAL) C[(size_t)crow * ldc + ccol] = v;
        if (WBF) Cb[(size_t)crow * ldc + ccol] = f2bf(v);
      }
    }
  }
}

// ---------- split-K combine: xdbl = sum of NSLICE slabs (fp32 + bf16) --------
__global__ __launch_bounds__(256) void combine_xdbl(
    const float* __restrict__ part, float* __restrict__ xdbl,
    unsigned short* __restrict__ xdbl_bf) {
  int i = blockIdx.x * 256 + threadIdx.x;
  const size_t slab = (size_t)ROWS * XP / 4;
  const float4* p = (const float4*)part;
  float4 s = make_float4(0.f, 0.f, 0.f, 0.f);
  #pragma unroll
  for (int z = 0; z < NSLICE; z++) {
    float4 a = p[i + (size_t)z * slab];
    s.x += a.x; s.y += a.y; s.z += a.z; s.w += a.w;
  }
  ((float4*)xdbl)[i] = s;
  ushort4 o;
  o.x = f2bf(s.x); o.y = f2bf(s.y); o.z = f2bf(s.z); o.w = f2bf(s.w);
  ((ushort4*)xdbl_bf)[i] = o;
}

// ---------- out_proj split-K combine: residual += part0 + part1 --------------
__global__ __launch_bounds__(256) void combine_residual(
    const float* __restrict__ part, float* __restrict__ residual) {
  int i = blockIdx.x * 256 + threadIdx.x;   // over ROWS*DMODEL/4 = 1M
  const size_t slab = (size_t)ROWS * DMODEL / 4;
  const float4* p = (const float4*)part;
  float4 a = p[i], b = p[i + slab];
  float4 r = ((const float4*)residual)[i];
  r.x += a.x + b.x;
  r.y += a.y + b.y;
  r.z += a.z + b.z;
  r.w += a.w + b.w;
  ((float4*)residual)[i] = r;
}

// ------- causal depthwise conv1d + SiLU: 8 ch x 4 rows per thread ------------
__global__ __launch_bounds__(256) void conv_silu_kernel(
    const unsigned short* __restrict__ xz, const float* __restrict__ cw,
    const float* __restrict__ cb, unsigned short* __restrict__ xbf) {
  int tid = blockIdx.x * 256 + threadIdx.x;   // ROWS/4 * DINNER/8 = 262144
  int dv = tid & (DINNER / 8 - 1);
  int rg = tid >> 8;                          // row group (4 rows)
  int l0 = (rg & (LSEQ / 4 - 1)) * 4;         // seq pos of first output row
  int row0 = rg * 4;
  int d = dv * 8;

  float4 wq[8];
  #pragma unroll
  for (int j = 0; j < 8; j++) wq[j] = ((const float4*)(cw + (size_t)d * DCONV))[j];
  float4 b0 = ((const float4*)(cb + d))[0];
  float4 b1 = ((const float4*)(cb + d))[1];
  const float bias[8] = {b0.x, b0.y, b0.z, b0.w, b1.x, b1.y, b1.z, b1.w};

  ushort8 xin[7];
  #pragma unroll
  for (int r = 0; r < 7; r++) {
    int l = l0 - 3 + r;
    if (l >= 0)
      xin[r] = *(const ushort8*)(xz + (size_t)(row0 - 3 + r) * (2 * DINNER) + d);
    else
      xin[r] = (ushort8){0, 0, 0, 0, 0, 0, 0, 0};
  }

  #pragma unroll
  for (int o = 0; o < 4; o++) {
    ushort8 ob;
    #pragma unroll
    for (int j = 0; j < 8; j++) {
      const float* wj = (const float*)&wq[j];
      float acc = bias[j];
      #pragma unroll
      for (int k = 0; k < DCONV; k++)
        acc = fmaf(bf2f(xin[o + k][j]), wj[k], acc);
      float s = acc / (1.f + __expf(-acc));
      ob[j] = f2bf(s);
    }
    *(ushort8*)(xbf + (size_t)(row0 + o) * DINNER + d) = ob;
  }
}

// ==== chunk-parallel selective scan (CLEN=32, LDS B/C, packed bf16 carries) ==
__global__ __launch_bounds__(256) void scan_p1(
    const float* __restrict__ delta, const unsigned short* __restrict__ u,
    const float* __restrict__ xdbl, const float* __restrict__ A_log,
    unsigned int* __restrict__ carrybuf) {
  int tid = blockIdx.x * 256 + threadIdx.x;   // B*NCHUNK*DINNER = 131072
  int t = threadIdx.x;
  int d = tid & (DINNER - 1);
  int chunk = (tid >> 11) & (NCHUNK - 1);
  int b = tid >> 17;
  int l0 = chunk * CLEN;

  __shared__ float bl[CLEN][16];              // B rows, 2 KB
  {
    const float4* src4 = (const float4*)(xdbl + ((size_t)b * LSEQ + l0) * XP);
    if (t < CLEN * 4) {
      int li = t >> 2, qi = t & 3;
      ((float4*)&bl[li][0])[qi] = src4[li * (XP / 4) + 16 + qi];
    }
  }
  __syncthreads();

  float A[DSTATE], st[DSTATE], ap[DSTATE];
  const float4* Ar = (const float4*)(A_log + d * DSTATE);
  #pragma unroll
  for (int q = 0; q < 4; q++) {
    float4 av = Ar[q];
    A[4 * q] = -__expf(av.x); A[4 * q + 1] = -__expf(av.y);
    A[4 * q + 2] = -__expf(av.z); A[4 * q + 3] = -__expf(av.w);
  }
  #pragma unroll
  for (int s = 0; s < DSTATE; s++) { st[s] = 0.f; ap[s] = 1.f; }

  const float* dptr = delta + ((size_t)b * LSEQ + l0) * DINNER + d;
  const unsigned short* uptr = u + ((size_t)b * LSEQ + l0) * DINNER + d;
  float dt_n = dptr[0];
  float uu_n = bf2f(uptr[0]);
  #pragma unroll 4
  for (int l = 0; l < CLEN; l++) {
    float dt = dt_n, uu = uu_n;
    if (l + 1 < CLEN) {
      dt_n = dptr[(size_t)(l + 1) * DINNER];
      uu_n = bf2f(uptr[(size_t)(l + 1) * DINNER]);
    }
    float du = dt * uu;
    #pragma unroll
    for (int q = 0; q < 4; q++) {
      float4 B4 = *(const float4*)&bl[l][q * 4];
      const float Bj[4] = {B4.x, B4.y, B4.z, B4.w};
      #pragma unroll
      for (int j = 0; j < 4; j++) {
        int s = 4 * q + j;
        float dA = __expf(dt * A[s]);
        st[s] = fmaf(dA, st[s], du * Bj[j]);
        ap[s] *= dA;
      }
    }
  }
  uint4v* co = (uint4v*)(carrybuf + (size_t)tid * DSTATE);
  #pragma unroll
  for (int q = 0; q < 4; q++) {
    uint4v v;
    #pragma unroll
    for (int j = 0; j < 4; j++)
      v[j] = ((unsigned int)f2bf(ap[4 * q + j]) << 16) | f2bf(st[4 * q + j]);
    co[q] = v;
  }
}

// P2: sequential combine over NCHUNK packed chunks; fp32 carry accumulation.
__global__ __launch_bounds__(256) void scan_p2(
    const unsigned int* __restrict__ cbuf, unsigned short* __restrict__ carryin) {
  int tid = blockIdx.x * 256 + threadIdx.x;   // B*DINNER*DSTATE = 65536
  int ds = tid & (DINNER * DSTATE - 1);
  int b = tid >> 15;
  float carry = 0.f;
  size_t base = (size_t)b * NCHUNK * DINNER * DSTATE + ds;
  const size_t cs = DINNER * DSTATE;
  for (int c = 0; c < NCHUNK; c += 4) {
    size_t i0 = base + (size_t)c * cs;
    unsigned int v0 = cbuf[i0], v1 = cbuf[i0 + cs];
    unsigned int v2 = cbuf[i0 + 2 * cs], v3 = cbuf[i0 + 3 * cs];
    carryin[i0] = f2bf(carry);
    carry = fmaf(bf2f(v0 >> 16), carry, bf2f(v0 & 0xFFFFu));
    carryin[i0 + cs] = f2bf(carry);
    carry = fmaf(bf2f(v1 >> 16), carry, bf2f(v1 & 0xFFFFu));
    carryin[i0 + 2 * cs] = f2bf(carry);
    carry = fmaf(bf2f(v2 >> 16), carry, bf2f(v2 & 0xFFFFu));
    carryin[i0 + 3 * cs] = f2bf(carry);
    carry = fmaf(bf2f(v3 >> 16), carry, bf2f(v3 & 0xFFFFu));
  }
}

// P3: seeded re-scan + y = (C.state + u*D) * silu(z); B/C from LDS.
__global__ __launch_bounds__(256) void scan_p3(
    const float* __restrict__ delta, const unsigned short* __restrict__ u,
    const float* __restrict__ xdbl, const unsigned short* __restrict__ xzbf,
    const float* __restrict__ A_log, const float* __restrict__ Dp,
    const unsigned short* __restrict__ carryin, unsigned short* __restrict__ ybf) {
  int tid = blockIdx.x * 256 + threadIdx.x;
  int t = threadIdx.x;
  int d = tid & (DINNER - 1);
  int chunk = (tid >> 11) & (NCHUNK - 1);
  int b = tid >> 17;
  int l0 = chunk * CLEN;

  __shared__ float bc[CLEN][32];              // B+C rows, 4 KB
  {
    const float4* src4 = (const float4*)(xdbl + ((size_t)b * LSEQ + l0) * XP);
    int li = t >> 3, qi = t & 7;              // 256 threads = 32 rows x 8 quads
    ((float4*)&bc[li][0])[qi] = src4[li * (XP / 4) + 16 + qi];
  }
  __syncthreads();

  float A[DSTATE], st[DSTATE];
  {
    const ushort8* ci8 = (const ushort8*)(carryin + (size_t)tid * DSTATE);
    ushort8 c0 = ci8[0], c1 = ci8[1];
    #pragma unroll
    for (int j = 0; j < 8; j++) { st[j] = bf2f(c0[j]); st[8 + j] = bf2f(c1[j]); }
  }
  const float4* Ar = (const float4*)(A_log + d * DSTATE);
  #pragma unroll
  for (int q = 0; q < 4; q++) {
    float4 av = Ar[q];
    A[4 * q] = -__expf(av.x); A[4 * q + 1] = -__expf(av.y);
    A[4 * q + 2] = -__expf(av.z); A[4 * q + 3] = -__expf(av.w);
  }
  float Dval = Dp[d];

  const float* dptr = delta + ((size_t)b * LSEQ + l0) * DINNER + d;
  const unsigned short* uptr = u + ((size_t)b * LSEQ + l0) * DINNER + d;
  const unsigned short* zptr = xzbf + ((size_t)b * LSEQ + l0) * (2 * DINNER) + DINNER + d;
  unsigned short* yptr = ybf + ((size_t)b * LSEQ + l0) * DINNER + d;

  float dt_n = dptr[0];
  float uu_n = bf2f(uptr[0]);
  float zz_n = bf2f(zptr[0]);
  #pragma unroll 4
  for (int l = 0; l < CLEN; l++) {
    float dt = dt_n, uu = uu_n, zz = zz_n;
    if (l + 1 < CLEN) {
      dt_n = dptr[(size_t)(l + 1) * DINNER];
      uu_n = bf2f(uptr[(size_t)(l + 1) * DINNER]);
      zz_n = bf2f(zptr[(size_t)(l + 1) * (2 * DINNER)]);
    }
    float du = dt * uu;
    #pragma unroll
    for (int q = 0; q < 4; q++) {
      float4 B4 = *(const float4*)&bc[l][q * 4];
      const float Bj[4] = {B4.x, B4.y, B4.z, B4.w};
      #pragma unroll
      for (int j = 0; j < 4; j++) {
        int s = 4 * q + j;
        float dA = __expf(dt * A[s]);
        st[s] = fmaf(dA, st[s], du * Bj[j]);
      }
    }
    float acc = 0.f;
    #pragma unroll
    for (int q = 0; q < 4; q++) {
      float4 C4 = *(const float4*)&bc[l][16 + q * 4];
      const float Cj[4] = {C4.x, C4.y, C4.z, C4.w};
      #pragma unroll
      for (int j = 0; j < 4; j++) acc = fmaf(st[4 * q + j], Cj[j], acc);
    }
    float yv = (acc + uu * Dval) * (zz / (1.f + __expf(-zz)));
    yptr[(size_t)l * DINNER] = f2bf(yv);
  }
}

extern "C" void kernel_launch(void* const* d_in, const int* in_sizes, int n_in,
                              void* d_out, int out_size, void* d_ws, size_t ws_size,
                              hipStream_t stream) {
  const float* hidden    = (const float*)d_in[0];
  const float* norm_w    = (const float*)d_in[1];
  const float* norm_b    = (const float*)d_in[2];
  const float* in_proj_w = (const float*)d_in[3];
  const float* conv_w    = (const float*)d_in[4];
  const float* conv_b    = (const float*)d_in[5];
  const float* x_proj_w  = (const float*)d_in[6];
  const float* dt_proj_w = (const float*)d_in[7];
  const float* dt_proj_b = (const float*)d_in[8];
  const float* A_log     = (const float*)d_in[9];
  const float* Dp        = (const float*)d_in[10];
  const float* out_proj_w= (const float*)d_in[11];
  const float* fnw       = (const float*)d_in[12];
  const float* fnb       = (const float*)d_in[13];
  float* out = (float*)d_out;

  const size_t CARRYSZ = (size_t)NBATCH * NCHUNK * DINNER * DSTATE;  // 4M entries

  // ---- workspace layout (≈150 MiB; 209.5 proven safe) ----
  float* residual = (float*)d_ws;                                   // 16 MiB
  float* delta    = residual + (size_t)ROWS * DMODEL;               // 32 MiB
  float* xdbl     = delta + (size_t)ROWS * DINNER;                  // 2 MiB
  float* fend     = xdbl + (size_t)ROWS * XP;

  unsigned short* xz_bf   = (unsigned short*)fend;                        // 32 MiB
  unsigned short* xbuf_bf = xz_bf + (size_t)ROWS * 2 * DINNER;            // 16 MiB
  unsigned short* h_bf    = xbuf_bf + (size_t)ROWS * DINNER;              // 8 MiB
  unsigned short* ybuf_bf = h_bf + (size_t)ROWS * DMODEL;                 // 16 MiB
  unsigned short* xdbl_bf = ybuf_bf + (size_t)ROWS * DINNER;              // 1 MiB
  unsigned short* xpw_bf  = xdbl_bf + (size_t)ROWS * XP;                  // 2 MiB
  unsigned short* dtw_bf  = xpw_bf + (size_t)N_LAYERS * XP * DINNER;      // 1 MiB
  unsigned short* ipw_bf  = dtw_bf + (size_t)N_LAYERS * DINNER * DTRANK;  // 8 MiB (per layer)
  unsigned short* opw_bf  = ipw_bf + (size_t)2 * DINNER * DMODEL;         // 4 MiB (per layer)
  unsigned short* usend   = opw_bf + (size_t)DMODEL * DINNER;

  unsigned int*   carrybuf = (unsigned int*)usend;                        // 16 MiB
  unsigned short* carryin  = (unsigned short*)(carrybuf + CARRYSZ);       // 8 MiB
  // delta region reuse (lifetime-disjoint): x_proj partials (16 MiB) before
  // dt_proj writes delta; out_proj partials (32 MiB) after scan_p3 reads delta.
  float*          xpart    = delta;
  float*          oppart   = delta;

  // one-time small weight conversions
  cvt_xpw<<<N_LAYERS * XP * DINNER / 4 / 256, 256, 0, stream>>>(x_proj_w, xpw_bf);
  {
    int n4 = N_LAYERS * DINNER * DTRANK / 4;
    cvt_f2bf<<<n4 / 256, 256, 0, stream>>>(dt_proj_w, dtw_bf, n4);
  }

  for (int i = 0; i < N_LAYERS; i++) {
    {
      int n4 = 2 * DINNER * DMODEL / 4;
      cvt_f2bf<<<n4 / 256, 256, 0, stream>>>(
          in_proj_w + (size_t)i * 2 * DINNER * DMODEL, ipw_bf, n4);
      n4 = DMODEL * DINNER / 4;
      cvt_f2bf<<<n4 / 256, 256, 0, stream>>>(
          out_proj_w + (size_t)i * DMODEL * DINNER, opw_bf, n4);
    }
    ln_kernel<true><<<ROWS, 256, 0, stream>>>(
        i == 0 ? hidden : residual, i == 0 ? residual : nullptr,
        norm_w + (size_t)i * DMODEL, norm_b + (size_t)i * DMODEL, h_bf);
    // in_proj -> xz bf16   (256x256 reg-staged 2-deep, grid 16x16)
    {
      dim3 g(2 * DINNER / 256, ROWS / 256);
      gemm256r<0, false, false, false, true><<<g, 512, 0, stream>>>(
          h_bf, DMODEL, ipw_bf, DMODEL, nullptr, 2 * DINNER, DMODEL,
          nullptr, nullptr, xz_bf);
    }
    conv_silu_kernel<<<ROWS / 4 * DINNER / 8 / 256, 256, 0, stream>>>(
        xz_bf, conv_w + (size_t)i * DINNER * DCONV, conv_b + (size_t)i * DINNER,
        xbuf_bf);
    // x_proj: split-K (8 x K=256, 256 blocks) -> partials, then combine
    {
      dim3 g(1, ROWS / 128, NSLICE);
      gemm_bf16<0, false, false, true, false, true><<<g, 256, 0, stream>>>(
          xbuf_bf, DINNER, xpw_bf + (size_t)i * XP * DINNER, DINNER,
          xpart, XP, KSLICE, nullptr, nullptr, nullptr);
      combine_xdbl<<<ROWS * XP / 4 / 256, 256, 0, stream>>>(xpart, xdbl, xdbl_bf);
    }
    // dt_proj + bias + softplus -> delta fp32  (128x128, grid 16x32)
    {
      dim3 g(DINNER / 128, ROWS / 128);
      gemm_bf16<1, true, false, true, false, false><<<g, 256, 0, stream>>>(
          xdbl_bf, XP, dtw_bf + (size_t)i * DINNER * DTRANK, DTRANK,
          delta, DINNER, DTRANK, dt_proj_b + (size_t)i * DINNER,
          nullptr, nullptr);
    }
    // chunk-parallel scan
    scan_p1<<<NBATCH * NCHUNK * DINNER / 256, 256, 0, stream>>>(
        delta, xbuf_bf, xdbl, A_log + (size_t)i * DINNER * DSTATE, carrybuf);
    scan_p2<<<NBATCH * DINNER * DSTATE / 256, 256, 0, stream>>>(carrybuf, carryin);
    scan_p3<<<NBATCH * NCHUNK * DINNER / 256, 256, 0, stream>>>(
        delta, xbuf_bf, xdbl, xz_bf, A_log + (size_t)i * DINNER * DSTATE,
        Dp + (size_t)i * DINNER, carryin, ybuf_bf);
    // out_proj: split-K (2 x K=1024, 512 blocks = 2/CU) -> partials in delta,
    // then residual += p0 + p1
    {
      dim3 g(DMODEL / 128, ROWS / 128, OPSLICE);
      gemm_bf16<0, false, false, false, false, true><<<g, 256, 0, stream>>>(
          ybuf_bf, DINNER, opw_bf, DINNER,
          oppart, DMODEL, DINNER / OPSLICE, nullptr, nullptr, nullptr);
      combine_residual<<<ROWS * DMODEL / 4 / 256, 256, 0, stream>>>(oppart, residual);
    }
  }
  ln_kernel<false><<<ROWS, 256, 0, stream>>>(residual, nullptr, fnw, fnb, out);
}

// Round 17
// 891.624 us; speedup vs baseline: 1.4044x; 1.4044x over previous
//
#include <hip/hip_runtime.h>
#include <math.h>

#define N_LAYERS 4
#define DMODEL 1024
#define DINNER 2048
#define DSTATE 16
#define DTRANK 64
#define DCONV 4
#define NBATCH 2
#define LSEQ 2048
#define LNEPS 1e-5f
#define ROWS (NBATCH * LSEQ)   // 4096
#define CLEN 32
#define NCHUNK (LSEQ / CLEN)   // 64
#define XP 128                 // padded x_proj output pitch (dt 0:64, B 64:80, C 80:96)
#define KSLICE 256             // x_proj split-K slice
#define NSLICE (DINNER / KSLICE)  // 8
#define OPSLICE 2              // out_proj split-K slices

typedef __attribute__((ext_vector_type(8))) short bf16x8;
typedef __attribute__((ext_vector_type(8))) unsigned short ushort8;
typedef __attribute__((ext_vector_type(4))) float f32x4;
typedef __attribute__((ext_vector_type(4))) unsigned int uint4v;

__device__ __forceinline__ unsigned short f2bf(float f) {
  unsigned int u = __float_as_uint(f);
  return (unsigned short)((u + 0x7FFFu + ((u >> 16) & 1u)) >> 16);  // RNE
}
__device__ __forceinline__ float bf2f(unsigned short h) {
  return __uint_as_float(((unsigned int)h) << 16);
}

__device__ __forceinline__ void gload16(const unsigned short* g, unsigned short* l) {
  __builtin_amdgcn_global_load_lds(
      (const __attribute__((address_space(1))) unsigned int*)g,
      (__attribute__((address_space(3))) unsigned int*)l, 16, 0, 0);
}

// fast softplus via HW v_exp/v_log (R7: libm version cost 100 us/layer)
__device__ __forceinline__ float softplus_f(float x) {
  float e = __expf(-fabsf(x));
  return fmaxf(x, 0.f) + __logf(1.f + e);
}

// ---------------- fp32 -> bf16 weight conversion -----------------------------
__global__ __launch_bounds__(256) void cvt_f2bf(const float* __restrict__ src,
                                                unsigned short* __restrict__ dst, int n4) {
  int i = blockIdx.x * 256 + threadIdx.x;
  if (i >= n4) return;
  float4 v = ((const float4*)src)[i];
  ushort4 o;
  o.x = f2bf(v.x); o.y = f2bf(v.y); o.z = f2bf(v.z); o.w = f2bf(v.w);
  ((ushort4*)dst)[i] = o;
}

// x_proj_w [4][96][2048] -> padded bf16 [4][128][2048] (rows 96..127 zero)
__global__ __launch_bounds__(256) void cvt_xpw(const float* __restrict__ src,
                                               unsigned short* __restrict__ dst) {
  int i = blockIdx.x * 256 + threadIdx.x;    // over 4*128*512
  int col4 = i & 511;
  int row = (i >> 9) & 127;
  int layer = i >> 16;
  float4 v = make_float4(0.f, 0.f, 0.f, 0.f);
  if (row < 96) v = ((const float4*)(src + ((size_t)layer * 96 + row) * 2048))[col4];
  ushort4 o;
  o.x = f2bf(v.x); o.y = f2bf(v.y); o.z = f2bf(v.z); o.w = f2bf(v.w);
  ((ushort4*)(dst + ((size_t)layer * 128 + row) * 2048))[col4] = o;
}

// ---------------- LayerNorm: fp32 in, bf16 (hidden path) or fp32 (final) out -
template<bool OBF>
__global__ __launch_bounds__(256) void ln_kernel(
    const float* __restrict__ src, float* __restrict__ res_copy,
    const float* __restrict__ w, const float* __restrict__ b, void* out) {
  int row = blockIdx.x;
  int t = threadIdx.x;
  const float4* srow = (const float4*)(src + (size_t)row * DMODEL);
  float4 v = srow[t];
  if (res_copy) ((float4*)(res_copy + (size_t)row * DMODEL))[t] = v;
  float s = v.x + v.y + v.z + v.w;
  float sq = v.x * v.x + v.y * v.y + v.z * v.z + v.w * v.w;
  #pragma unroll
  for (int o = 32; o >= 1; o >>= 1) {
    s += __shfl_xor(s, o);
    sq += __shfl_xor(sq, o);
  }
  __shared__ float ss[4], ssq[4];
  int wid = t >> 6, lane = t & 63;
  if (lane == 0) { ss[wid] = s; ssq[wid] = sq; }
  __syncthreads();
  s = ss[0] + ss[1] + ss[2] + ss[3];
  sq = ssq[0] + ssq[1] + ssq[2] + ssq[3];
  float mu = s * (1.f / DMODEL);
  float var = sq * (1.f / DMODEL) - mu * mu;
  float rs = rsqrtf(var + LNEPS);
  float4 wv = ((const float4*)w)[t];
  float4 bv = ((const float4*)b)[t];
  float4 o4;
  o4.x = (v.x - mu) * rs * wv.x + bv.x;
  o4.y = (v.y - mu) * rs * wv.y + bv.y;
  o4.z = (v.z - mu) * rs * wv.z + bv.z;
  o4.w = (v.w - mu) * rs * wv.w + bv.w;
  if (OBF) {
    ushort4 ob;
    ob.x = f2bf(o4.x); ob.y = f2bf(o4.y); ob.z = f2bf(o4.z); ob.w = f2bf(o4.w);
    ((ushort4*)((unsigned short*)out + (size_t)row * DMODEL))[t] = ob;
  } else {
    ((float4*)((float*)out + (size_t)row * DMODEL))[t] = o4;
  }
}

// ==== 256x256 bf16 MFMA GEMM, reg-staged + padded LDS (R15-proven, 1-deep) ===
// R16 post-mortem: 2-deep reg prefetch spilled to scratch (WRITE_SIZE 329 MB).
// This is the R15 version: 51 us on in_proj, bank conflicts 3.1M.
template<int ACT, bool BIAS, bool ADD, bool WF32, bool WBF>
__global__ __launch_bounds__(512) void gemm256r(
    const unsigned short* __restrict__ A, int lda,
    const unsigned short* __restrict__ W, int ldw,
    float* __restrict__ C, int ldc, int K,
    const float* __restrict__ bias,
    const float* __restrict__ addsrc,
    unsigned short* __restrict__ Cb) {
  __shared__ unsigned short lds[2][256][72];   // 72 KB, +16B/row pad
  const int t = threadIdx.x;
  const int lane = t & 63;
  const int wave = t >> 6;
  const int wr = wave >> 2;          // 0..1 (M half)
  const int wc = wave & 3;           // 0..3 (N quarter)
  const int m0 = blockIdx.y * 256, n0 = blockIdx.x * 256;
  const int frow = lane & 15;
  const int hi = lane >> 4;

  const int srow = t >> 3;           // staging row base 0..63 (+64*r)
  const int sc8 = (t & 7) << 3;      // staging chunk col (elements)

  f32x4 acc[8][4];
  #pragma unroll
  for (int m = 0; m < 8; m++)
    #pragma unroll
    for (int n = 0; n < 4; n++) acc[m][n] = (f32x4){0.f, 0.f, 0.f, 0.f};

  const int NT = K / 64;
  ushort8 areg[4], wreg[4];

  auto loadreg = [&](int kt) {
    #pragma unroll
    for (int r = 0; r < 4; ++r) {
      int row = srow + (r << 6);
      areg[r] = *(const ushort8*)(A + (size_t)(m0 + row) * lda + kt * 64 + sc8);
      wreg[r] = *(const ushort8*)(W + (size_t)(n0 + row) * ldw + kt * 64 + sc8);
    }
  };
  auto dswrite = [&]() {
    #pragma unroll
    for (int r = 0; r < 4; ++r) {
      int row = srow + (r << 6);
      *(ushort8*)&lds[0][row][sc8] = areg[r];
      *(ushort8*)&lds[1][row][sc8] = wreg[r];
    }
  };
  auto compute = [&]() {
    #pragma unroll
    for (int ks = 0; ks < 2; ++ks) {
      bf16x8 a[8], b[4];
      #pragma unroll
      for (int m = 0; m < 8; ++m)
        a[m] = *(const bf16x8*)&lds[0][wr * 128 + m * 16 + frow][(ks * 4 + hi) << 3];
      #pragma unroll
      for (int n = 0; n < 4; ++n)
        b[n] = *(const bf16x8*)&lds[1][wc * 64 + n * 16 + frow][(ks * 4 + hi) << 3];
      __builtin_amdgcn_s_setprio(1);
      #pragma unroll
      for (int m = 0; m < 8; ++m)
        #pragma unroll
        for (int n = 0; n < 4; ++n)
          acc[m][n] = __builtin_amdgcn_mfma_f32_16x16x32_bf16(a[m], b[n], acc[m][n], 0, 0, 0);
      __builtin_amdgcn_s_setprio(0);
    }
  };

  loadreg(0);
  dswrite();
  __syncthreads();
  for (int kt = 0; kt < NT; ++kt) {
    if (kt + 1 < NT) loadreg(kt + 1);   // issue early; lands during compute
    compute();
    __syncthreads();                    // all waves done reading this tile
    if (kt + 1 < NT) {
      dswrite();                        // waits on its own loads only
      __syncthreads();                  // writes visible before next compute
    }
  }

  #pragma unroll
  for (int m = 0; m < 8; ++m) {
    int rbase = m0 + wr * 128 + m * 16 + hi * 4;
    #pragma unroll
    for (int n = 0; n < 4; ++n) {
      int ccol = n0 + wc * 64 + n * 16 + frow;
      #pragma unroll
      for (int j = 0; j < 4; ++j) {
        int crow = rbase + j;
        float v = acc[m][n][j];
        if (BIAS) v += bias[ccol];
        if (ACT == 1) v = softplus_f(v);
        if (ADD) v += addsrc[(size_t)crow * ldc + ccol];
        if (WF32) C[(size_t)crow * ldc + ccol] = v;
        if (WBF) Cb[(size_t)crow * ldc + ccol] = f2bf(v);
      }
    }
  }
}

// ------------- 128x128 2-phase GEMM (R12-proven; dt/x/out_proj) --------------
template<int ACT, bool BIAS, bool ADD, bool WF32, bool WBF, bool PARTIAL>
__global__ __launch_bounds__(256) void gemm_bf16(
    const unsigned short* __restrict__ A, int lda,
    const unsigned short* __restrict__ W, int ldw,
    float* __restrict__ C, int ldc, int K,
    const float* __restrict__ bias,
    const float* __restrict__ addsrc,
    unsigned short* __restrict__ Cb) {
  __shared__ unsigned short As[2][128][32];
  __shared__ unsigned short Ws[2][128][32];
  int t = threadIdx.x;
  int lane = t & 63, wave = t >> 6;
  int wr = wave >> 1, wc = wave & 1;
  int m0 = blockIdx.y * 128, n0 = blockIdx.x * 128;

  int kbase = 0;
  if (PARTIAL) {
    kbase = blockIdx.z * K;
    C += (size_t)blockIdx.z * (size_t)gridDim.y * 128 * ldc;
  }

  int r0 = t >> 2;
  int kk8 = (t & 3) << 3;
  const unsigned short* Ag = A + (size_t)(m0 + r0) * lda + kbase + kk8;
  const unsigned short* Wg = W + (size_t)(n0 + r0) * ldw + kbase + kk8;
  const size_t Astep = (size_t)64 * lda;
  const size_t Wstep = (size_t)64 * ldw;

  f32x4 zero = {0.f, 0.f, 0.f, 0.f};
  f32x4 acc[4][4];
  #pragma unroll
  for (int m = 0; m < 4; m++)
    #pragma unroll
    for (int n = 0; n < 4; n++) acc[m][n] = zero;

  int frow = lane & 15;
  int fk = (lane >> 4) << 3;

  auto stage = [&](int buf, int kt) {
    const unsigned short* ag = Ag + kt * 32;
    const unsigned short* wg = Wg + kt * 32;
    unsigned short* la = &As[buf][r0][kk8];
    unsigned short* lw = &Ws[buf][r0][kk8];
    gload16(ag, la);
    gload16(ag + Astep, la + 64 * 32);
    gload16(wg, lw);
    gload16(wg + Wstep, lw + 64 * 32);
  };
  auto compute = [&](int buf) {
    bf16x8 af[4], bw[4];
    #pragma unroll
    for (int m = 0; m < 4; m++)
      af[m] = *(const bf16x8*)&As[buf][wr * 64 + m * 16 + frow][fk];
    #pragma unroll
    for (int n = 0; n < 4; n++)
      bw[n] = *(const bf16x8*)&Ws[buf][wc * 64 + n * 16 + frow][fk];
    #pragma unroll
    for (int m = 0; m < 4; m++)
      #pragma unroll
      for (int n = 0; n < 4; n++)
        acc[m][n] = __builtin_amdgcn_mfma_f32_16x16x32_bf16(af[m], bw[n], acc[m][n], 0, 0, 0);
  };

  const int NT = K / 32;
  stage(0, 0);
  __syncthreads();
  int cur = 0;
  for (int kt = 0; kt < NT - 1; ++kt) {
    stage(cur ^ 1, kt + 1);
    compute(cur);
    __syncthreads();
    cur ^= 1;
  }
  compute(cur);

  #pragma unroll
  for (int m = 0; m < 4; m++) {
    int rbase = m0 + wr * 64 + m * 16 + ((lane >> 4) << 2);
    #pragma unroll
    for (int n = 0; n < 4; n++) {
      int ccol = n0 + wc * 64 + n * 16 + (lane & 15);
      #pragma unroll
      for (int j = 0; j < 4; j++) {
        int crow = rbase + j;
        float v = acc[m][n][j];
        if (BIAS) v += bias[ccol];
        if (ACT == 1) v = softplus_f(v);
        if (ADD) v += addsrc[(size_t)crow * ldc + ccol];
        if (WF32 || PARTIAL) C[(size_t)crow * ldc + ccol] = v;
        if (WBF) Cb[(size_t)crow * ldc + ccol] = f2bf(v);
      }
    }
  }
}

// ---------- split-K combine: xdbl = sum of NSLICE slabs (fp32 + bf16) --------
__global__ __launch_bounds__(256) void combine_xdbl(
    const float* __restrict__ part, float* __restrict__ xdbl,
    unsigned short* __restrict__ xdbl_bf) {
  int i = blockIdx.x * 256 + threadIdx.x;
  const size_t slab = (size_t)ROWS * XP / 4;
  const float4* p = (const float4*)part;
  float4 s = make_float4(0.f, 0.f, 0.f, 0.f);
  #pragma unroll
  for (int z = 0; z < NSLICE; z++) {
    float4 a = p[i + (size_t)z * slab];
    s.x += a.x; s.y += a.y; s.z += a.z; s.w += a.w;
  }
  ((float4*)xdbl)[i] = s;
  ushort4 o;
  o.x = f2bf(s.x); o.y = f2bf(s.y); o.z = f2bf(s.z); o.w = f2bf(s.w);
  ((ushort4*)xdbl_bf)[i] = o;
}

// ---------- out_proj split-K combine: residual += part0 + part1 --------------
__global__ __launch_bounds__(256) void combine_residual(
    const float* __restrict__ part, float* __restrict__ residual) {
  int i = blockIdx.x * 256 + threadIdx.x;   // over ROWS*DMODEL/4 = 1M
  const size_t slab = (size_t)ROWS * DMODEL / 4;
  const float4* p = (const float4*)part;
  float4 a = p[i], b = p[i + slab];
  float4 r = ((const float4*)residual)[i];
  r.x += a.x + b.x;
  r.y += a.y + b.y;
  r.z += a.z + b.z;
  r.w += a.w + b.w;
  ((float4*)residual)[i] = r;
}

// ------- causal depthwise conv1d + SiLU: 8 ch x 4 rows per thread ------------
__global__ __launch_bounds__(256) void conv_silu_kernel(
    const unsigned short* __restrict__ xz, const float* __restrict__ cw,
    const float* __restrict__ cb, unsigned short* __restrict__ xbf) {
  int tid = blockIdx.x * 256 + threadIdx.x;   // ROWS/4 * DINNER/8 = 262144
  int dv = tid & (DINNER / 8 - 1);
  int rg = tid >> 8;                          // row group (4 rows)
  int l0 = (rg & (LSEQ / 4 - 1)) * 4;         // seq pos of first output row
  int row0 = rg * 4;
  int d = dv * 8;

  float4 wq[8];
  #pragma unroll
  for (int j = 0; j < 8; j++) wq[j] = ((const float4*)(cw + (size_t)d * DCONV))[j];
  float4 b0 = ((const float4*)(cb + d))[0];
  float4 b1 = ((const float4*)(cb + d))[1];
  const float bias[8] = {b0.x, b0.y, b0.z, b0.w, b1.x, b1.y, b1.z, b1.w};

  ushort8 xin[7];
  #pragma unroll
  for (int r = 0; r < 7; r++) {
    int l = l0 - 3 + r;
    if (l >= 0)
      xin[r] = *(const ushort8*)(xz + (size_t)(row0 - 3 + r) * (2 * DINNER) + d);
    else
      xin[r] = (ushort8){0, 0, 0, 0, 0, 0, 0, 0};
  }

  #pragma unroll
  for (int o = 0; o < 4; o++) {
    ushort8 ob;
    #pragma unroll
    for (int j = 0; j < 8; j++) {
      const float* wj = (const float*)&wq[j];
      float acc = bias[j];
      #pragma unroll
      for (int k = 0; k < DCONV; k++)
        acc = fmaf(bf2f(xin[o + k][j]), wj[k], acc);
      float s = acc / (1.f + __expf(-acc));
      ob[j] = f2bf(s);
    }
    *(ushort8*)(xbf + (size_t)(row0 + o) * DINNER + d) = ob;
  }
}

// ==== chunk-parallel selective scan (CLEN=32, LDS B/C, packed bf16 carries,
//      bf16 delta) =============================================================
__global__ __launch_bounds__(256) void scan_p1(
    const unsigned short* __restrict__ delta, const unsigned short* __restrict__ u,
    const float* __restrict__ xdbl, const float* __restrict__ A_log,
    unsigned int* __restrict__ carrybuf) {
  int tid = blockIdx.x * 256 + threadIdx.x;   // B*NCHUNK*DINNER = 131072
  int t = threadIdx.x;
  int d = tid & (DINNER - 1);
  int chunk = (tid >> 11) & (NCHUNK - 1);
  int b = tid >> 17;
  int l0 = chunk * CLEN;

  __shared__ float bl[CLEN][16];              // B rows, 2 KB
  {
    const float4* src4 = (const float4*)(xdbl + ((size_t)b * LSEQ + l0) * XP);
    if (t < CLEN * 4) {
      int li = t >> 2, qi = t & 3;
      ((float4*)&bl[li][0])[qi] = src4[li * (XP / 4) + 16 + qi];
    }
  }
  __syncthreads();

  float A[DSTATE], st[DSTATE], ap[DSTATE];
  const float4* Ar = (const float4*)(A_log + d * DSTATE);
  #pragma unroll
  for (int q = 0; q < 4; q++) {
    float4 av = Ar[q];
    A[4 * q] = -__expf(av.x); A[4 * q + 1] = -__expf(av.y);
    A[4 * q + 2] = -__expf(av.z); A[4 * q + 3] = -__expf(av.w);
  }
  #pragma unroll
  for (int s = 0; s < DSTATE; s++) { st[s] = 0.f; ap[s] = 1.f; }

  const unsigned short* dptr = delta + ((size_t)b * LSEQ + l0) * DINNER + d;
  const unsigned short* uptr = u + ((size_t)b * LSEQ + l0) * DINNER + d;
  float dt_n = bf2f(dptr[0]);
  float uu_n = bf2f(uptr[0]);
  #pragma unroll 4
  for (int l = 0; l < CLEN; l++) {
    float dt = dt_n, uu = uu_n;
    if (l + 1 < CLEN) {
      dt_n = bf2f(dptr[(size_t)(l + 1) * DINNER]);
      uu_n = bf2f(uptr[(size_t)(l + 1) * DINNER]);
    }
    float du = dt * uu;
    #pragma unroll
    for (int q = 0; q < 4; q++) {
      float4 B4 = *(const float4*)&bl[l][q * 4];
      const float Bj[4] = {B4.x, B4.y, B4.z, B4.w};
      #pragma unroll
      for (int j = 0; j < 4; j++) {
        int s = 4 * q + j;
        float dA = __expf(dt * A[s]);
        st[s] = fmaf(dA, st[s], du * Bj[j]);
        ap[s] *= dA;
      }
    }
  }
  uint4v* co = (uint4v*)(carrybuf + (size_t)tid * DSTATE);
  #pragma unroll
  for (int q = 0; q < 4; q++) {
    uint4v v;
    #pragma unroll
    for (int j = 0; j < 4; j++)
      v[j] = ((unsigned int)f2bf(ap[4 * q + j]) << 16) | f2bf(st[4 * q + j]);
    co[q] = v;
  }
}

// P2: sequential combine over NCHUNK packed chunks; fp32 carry accumulation.
__global__ __launch_bounds__(256) void scan_p2(
    const unsigned int* __restrict__ cbuf, unsigned short* __restrict__ carryin) {
  int tid = blockIdx.x * 256 + threadIdx.x;   // B*DINNER*DSTATE = 65536
  int ds = tid & (DINNER * DSTATE - 1);
  int b = tid >> 15;
  float carry = 0.f;
  size_t base = (size_t)b * NCHUNK * DINNER * DSTATE + ds;
  const size_t cs = DINNER * DSTATE;
  for (int c = 0; c < NCHUNK; c += 4) {
    size_t i0 = base + (size_t)c * cs;
    unsigned int v0 = cbuf[i0], v1 = cbuf[i0 + cs];
    unsigned int v2 = cbuf[i0 + 2 * cs], v3 = cbuf[i0 + 3 * cs];
    carryin[i0] = f2bf(carry);
    carry = fmaf(bf2f(v0 >> 16), carry, bf2f(v0 & 0xFFFFu));
    carryin[i0 + cs] = f2bf(carry);
    carry = fmaf(bf2f(v1 >> 16), carry, bf2f(v1 & 0xFFFFu));
    carryin[i0 + 2 * cs] = f2bf(carry);
    carry = fmaf(bf2f(v2 >> 16), carry, bf2f(v2 & 0xFFFFu));
    carryin[i0 + 3 * cs] = f2bf(carry);
    carry = fmaf(bf2f(v3 >> 16), carry, bf2f(v3 & 0xFFFFu));
  }
}

// P3: seeded re-scan + y = (C.state + u*D) * silu(z); B/C from LDS.
__global__ __launch_bounds__(256) void scan_p3(
    const unsigned short* __restrict__ delta, const unsigned short* __restrict__ u,
    const float* __restrict__ xdbl, const unsigned short* __restrict__ xzbf,
    const float* __restrict__ A_log, const float* __restrict__ Dp,
    const unsigned short* __restrict__ carryin, unsigned short* __restrict__ ybf) {
  int tid = blockIdx.x * 256 + threadIdx.x;
  int t = threadIdx.x;
  int d = tid & (DINNER - 1);
  int chunk = (tid >> 11) & (NCHUNK - 1);
  int b = tid >> 17;
  int l0 = chunk * CLEN;

  __shared__ float bc[CLEN][32];              // B+C rows, 4 KB
  {
    const float4* src4 = (const float4*)(xdbl + ((size_t)b * LSEQ + l0) * XP);
    int li = t >> 3, qi = t & 7;              // 256 threads = 32 rows x 8 quads
    ((float4*)&bc[li][0])[qi] = src4[li * (XP / 4) + 16 + qi];
  }
  __syncthreads();

  float A[DSTATE], st[DSTATE];
  {
    const ushort8* ci8 = (const ushort8*)(carryin + (size_t)tid * DSTATE);
    ushort8 c0 = ci8[0], c1 = ci8[1];
    #pragma unroll
    for (int j = 0; j < 8; j++) { st[j] = bf2f(c0[j]); st[8 + j] = bf2f(c1[j]); }
  }
  const float4* Ar = (const float4*)(A_log + d * DSTATE);
  #pragma unroll
  for (int q = 0; q < 4; q++) {
    float4 av = Ar[q];
    A[4 * q] = -__expf(av.x); A[4 * q + 1] = -__expf(av.y);
    A[4 * q + 2] = -__expf(av.z); A[4 * q + 3] = -__expf(av.w);
  }
  float Dval = Dp[d];

  const unsigned short* dptr = delta + ((size_t)b * LSEQ + l0) * DINNER + d;
  const unsigned short* uptr = u + ((size_t)b * LSEQ + l0) * DINNER + d;
  const unsigned short* zptr = xzbf + ((size_t)b * LSEQ + l0) * (2 * DINNER) + DINNER + d;
  unsigned short* yptr = ybf + ((size_t)b * LSEQ + l0) * DINNER + d;

  float dt_n = bf2f(dptr[0]);
  float uu_n = bf2f(uptr[0]);
  float zz_n = bf2f(zptr[0]);
  #pragma unroll 4
  for (int l = 0; l < CLEN; l++) {
    float dt = dt_n, uu = uu_n, zz = zz_n;
    if (l + 1 < CLEN) {
      dt_n = bf2f(dptr[(size_t)(l + 1) * DINNER]);
      uu_n = bf2f(uptr[(size_t)(l + 1) * DINNER]);
      zz_n = bf2f(zptr[(size_t)(l + 1) * (2 * DINNER)]);
    }
    float du = dt * uu;
    #pragma unroll
    for (int q = 0; q < 4; q++) {
      float4 B4 = *(const float4*)&bc[l][q * 4];
      const float Bj[4] = {B4.x, B4.y, B4.z, B4.w};
      #pragma unroll
      for (int j = 0; j < 4; j++) {
        int s = 4 * q + j;
        float dA = __expf(dt * A[s]);
        st[s] = fmaf(dA, st[s], du * Bj[j]);
      }
    }
    float acc = 0.f;
    #pragma unroll
    for (int q = 0; q < 4; q++) {
      float4 C4 = *(const float4*)&bc[l][16 + q * 4];
      const float Cj[4] = {C4.x, C4.y, C4.z, C4.w};
      #pragma unroll
      for (int j = 0; j < 4; j++) acc = fmaf(st[4 * q + j], Cj[j], acc);
    }
    float yv = (acc + uu * Dval) * (zz / (1.f + __expf(-zz)));
    yptr[(size_t)l * DINNER] = f2bf(yv);
  }
}

extern "C" void kernel_launch(void* const* d_in, const int* in_sizes, int n_in,
                              void* d_out, int out_size, void* d_ws, size_t ws_size,
                              hipStream_t stream) {
  const float* hidden    = (const float*)d_in[0];
  const float* norm_w    = (const float*)d_in[1];
  const float* norm_b    = (const float*)d_in[2];
  const float* in_proj_w = (const float*)d_in[3];
  const float* conv_w    = (const float*)d_in[4];
  const float* conv_b    = (const float*)d_in[5];
  const float* x_proj_w  = (const float*)d_in[6];
  const float* dt_proj_w = (const float*)d_in[7];
  const float* dt_proj_b = (const float*)d_in[8];
  const float* A_log     = (const float*)d_in[9];
  const float* Dp        = (const float*)d_in[10];
  const float* out_proj_w= (const float*)d_in[11];
  const float* fnw       = (const float*)d_in[12];
  const float* fnb       = (const float*)d_in[13];
  float* out = (float*)d_out;

  const size_t CARRYSZ = (size_t)NBATCH * NCHUNK * DINNER * DSTATE;  // 4M entries

  // ---- workspace layout (≈150 MiB; 209.5 proven safe) ----
  float* residual = (float*)d_ws;                                   // 16 MiB
  float* dregion  = residual + (size_t)ROWS * DMODEL;               // 32 MiB multi-use
  float* xdbl     = dregion + (size_t)ROWS * DINNER;                // 2 MiB
  float* fend     = xdbl + (size_t)ROWS * XP;

  unsigned short* xz_bf   = (unsigned short*)fend;                        // 32 MiB
  unsigned short* xbuf_bf = xz_bf + (size_t)ROWS * 2 * DINNER;            // 16 MiB
  unsigned short* h_bf    = xbuf_bf + (size_t)ROWS * DINNER;              // 8 MiB
  unsigned short* ybuf_bf = h_bf + (size_t)ROWS * DMODEL;                 // 16 MiB
  unsigned short* xdbl_bf = ybuf_bf + (size_t)ROWS * DINNER;              // 1 MiB
  unsigned short* xpw_bf  = xdbl_bf + (size_t)ROWS * XP;                  // 2 MiB
  unsigned short* dtw_bf  = xpw_bf + (size_t)N_LAYERS * XP * DINNER;      // 1 MiB
  unsigned short* ipw_bf  = dtw_bf + (size_t)N_LAYERS * DINNER * DTRANK;  // 8 MiB (per layer)
  unsigned short* opw_bf  = ipw_bf + (size_t)2 * DINNER * DMODEL;         // 4 MiB (per layer)
  unsigned short* usend   = opw_bf + (size_t)DMODEL * DINNER;

  unsigned int*   carrybuf = (unsigned int*)usend;                        // 16 MiB
  unsigned short* carryin  = (unsigned short*)(carrybuf + CARRYSZ);       // 8 MiB
  // dregion multi-use (lifetime-disjoint, stream-ordered):
  //   x_proj partials (16 MiB) -> dt_proj writes delta_bf (8 MiB) ->
  //   p1/p3 read delta_bf -> out_proj partials (32 MiB)
  float*          xpart    = dregion;
  unsigned short* delta_bf = (unsigned short*)dregion;
  float*          oppart   = dregion;

  // one-time small weight conversions
  cvt_xpw<<<N_LAYERS * XP * DINNER / 4 / 256, 256, 0, stream>>>(x_proj_w, xpw_bf);
  {
    int n4 = N_LAYERS * DINNER * DTRANK / 4;
    cvt_f2bf<<<n4 / 256, 256, 0, stream>>>(dt_proj_w, dtw_bf, n4);
  }

  for (int i = 0; i < N_LAYERS; i++) {
    {
      int n4 = 2 * DINNER * DMODEL / 4;
      cvt_f2bf<<<n4 / 256, 256, 0, stream>>>(
          in_proj_w + (size_t)i * 2 * DINNER * DMODEL, ipw_bf, n4);
      n4 = DMODEL * DINNER / 4;
      cvt_f2bf<<<n4 / 256, 256, 0, stream>>>(
          out_proj_w + (size_t)i * DMODEL * DINNER, opw_bf, n4);
    }
    ln_kernel<true><<<ROWS, 256, 0, stream>>>(
        i == 0 ? hidden : residual, i == 0 ? residual : nullptr,
        norm_w + (size_t)i * DMODEL, norm_b + (size_t)i * DMODEL, h_bf);
    // in_proj -> xz bf16   (256x256 reg-staged, grid 16x16)
    {
      dim3 g(2 * DINNER / 256, ROWS / 256);
      gemm256r<0, false, false, false, true><<<g, 512, 0, stream>>>(
          h_bf, DMODEL, ipw_bf, DMODEL, nullptr, 2 * DINNER, DMODEL,
          nullptr, nullptr, xz_bf);
    }
    conv_silu_kernel<<<ROWS / 4 * DINNER / 8 / 256, 256, 0, stream>>>(
        xz_bf, conv_w + (size_t)i * DINNER * DCONV, conv_b + (size_t)i * DINNER,
        xbuf_bf);
    // x_proj: split-K (8 x K=256, 256 blocks) -> partials, then combine
    {
      dim3 g(1, ROWS / 128, NSLICE);
      gemm_bf16<0, false, false, true, false, true><<<g, 256, 0, stream>>>(
          xbuf_bf, DINNER, xpw_bf + (size_t)i * XP * DINNER, DINNER,
          xpart, XP, KSLICE, nullptr, nullptr, nullptr);
      combine_xdbl<<<ROWS * XP / 4 / 256, 256, 0, stream>>>(xpart, xdbl, xdbl_bf);
    }
    // dt_proj + bias + softplus -> delta bf16  (128x128, grid 16x32)
    {
      dim3 g(DINNER / 128, ROWS / 128);
      gemm_bf16<1, true, false, false, true, false><<<g, 256, 0, stream>>>(
          xdbl_bf, XP, dtw_bf + (size_t)i * DINNER * DTRANK, DTRANK,
          nullptr, DINNER, DTRANK, dt_proj_b + (size_t)i * DINNER,
          nullptr, delta_bf);
    }
    // chunk-parallel scan
    scan_p1<<<NBATCH * NCHUNK * DINNER / 256, 256, 0, stream>>>(
        delta_bf, xbuf_bf, xdbl, A_log + (size_t)i * DINNER * DSTATE, carrybuf);
    scan_p2<<<NBATCH * DINNER * DSTATE / 256, 256, 0, stream>>>(carrybuf, carryin);
    scan_p3<<<NBATCH * NCHUNK * DINNER / 256, 256, 0, stream>>>(
        delta_bf, xbuf_bf, xdbl, xz_bf, A_log + (size_t)i * DINNER * DSTATE,
        Dp + (size_t)i * DINNER, carryin, ybuf_bf);
    // out_proj: split-K (2 x K=1024, 512 blocks = 2/CU) -> partials, combine
    {
      dim3 g(DMODEL / 128, ROWS / 128, OPSLICE);
      gemm_bf16<0, false, false, false, false, true><<<g, 256, 0, stream>>>(
          ybuf_bf, DINNER, opw_bf, DINNER,
          oppart, DMODEL, DINNER / OPSLICE, nullptr, nullptr, nullptr);
      combine_residual<<<ROWS * DMODEL / 4 / 256, 256, 0, stream>>>(oppart, residual);
    }
  }
  ln_kernel<false><<<ROWS, 256, 0, stream>>>(residual, nullptr, fnw, fnb, out);
}

// Round 18
// 868.821 us; speedup vs baseline: 1.4413x; 1.0262x over previous
//
#include <hip/hip_runtime.h>
#include <math.h>

#define N_LAYERS 4
#define DMODEL 1024
#define DINNER 2048
#define DSTATE 16
#define DTRANK 64
#define DCONV 4
#define NBATCH 2
#define LSEQ 2048
#define LNEPS 1e-5f
#define ROWS (NBATCH * LSEQ)   // 4096
#define CLEN 32
#define NCHUNK (LSEQ / CLEN)   // 64
#define XP 128                 // padded x_proj output pitch (dt 0:64, B 64:80, C 80:96)
#define KSLICE 256             // x_proj split-K slice
#define NSLICE (DINNER / KSLICE)  // 8
#define OPSLICE 2              // out_proj split-K slices

typedef __attribute__((ext_vector_type(8))) short bf16x8;
typedef __attribute__((ext_vector_type(8))) unsigned short ushort8;
typedef __attribute__((ext_vector_type(4))) float f32x4;
typedef __attribute__((ext_vector_type(4))) unsigned int uint4v;

__device__ __forceinline__ unsigned short f2bf(float f) {
  unsigned int u = __float_as_uint(f);
  return (unsigned short)((u + 0x7FFFu + ((u >> 16) & 1u)) >> 16);  // RNE
}
__device__ __forceinline__ float bf2f(unsigned short h) {
  return __uint_as_float(((unsigned int)h) << 16);
}

__device__ __forceinline__ void gload16(const unsigned short* g, unsigned short* l) {
  __builtin_amdgcn_global_load_lds(
      (const __attribute__((address_space(1))) unsigned int*)g,
      (__attribute__((address_space(3))) unsigned int*)l, 16, 0, 0);
}

// fast softplus via HW v_exp/v_log (R7: libm version cost 100 us/layer)
__device__ __forceinline__ float softplus_f(float x) {
  float e = __expf(-fabsf(x));
  return fmaxf(x, 0.f) + __logf(1.f + e);
}

// ---------------- fp32 -> bf16 weight conversion -----------------------------
__global__ __launch_bounds__(256) void cvt_f2bf(const float* __restrict__ src,
                                                unsigned short* __restrict__ dst, int n4) {
  int i = blockIdx.x * 256 + threadIdx.x;
  if (i >= n4) return;
  float4 v = ((const float4*)src)[i];
  ushort4 o;
  o.x = f2bf(v.x); o.y = f2bf(v.y); o.z = f2bf(v.z); o.w = f2bf(v.w);
  ((ushort4*)dst)[i] = o;
}

// x_proj_w [4][96][2048] -> padded bf16 [4][128][2048] (rows 96..127 zero)
__global__ __launch_bounds__(256) void cvt_xpw(const float* __restrict__ src,
                                               unsigned short* __restrict__ dst) {
  int i = blockIdx.x * 256 + threadIdx.x;    // over 4*128*512
  int col4 = i & 511;
  int row = (i >> 9) & 127;
  int layer = i >> 16;
  float4 v = make_float4(0.f, 0.f, 0.f, 0.f);
  if (row < 96) v = ((const float4*)(src + ((size_t)layer * 96 + row) * 2048))[col4];
  ushort4 o;
  o.x = f2bf(v.x); o.y = f2bf(v.y); o.z = f2bf(v.z); o.w = f2bf(v.w);
  ((ushort4*)(dst + ((size_t)layer * 128 + row) * 2048))[col4] = o;
}

// ---- LayerNorm with fused out_proj split-K combine (R18) --------------------
// MODE 0: v = src            ; residual <- v ; bf16 LN out   (layer 0)
// MODE 1: v = src + p0 + p1  ; residual <- v ; bf16 LN out   (layers 1..3)
// MODE 2: v = src + p0 + p1  ;                 fp32 LN out   (final)
template<int MODE>
__global__ __launch_bounds__(256) void ln_kernel(
    const float* __restrict__ src, const float* __restrict__ parts,
    const float* __restrict__ w, const float* __restrict__ b,
    void* out, float* __restrict__ res_out) {
  int row = blockIdx.x;
  int t = threadIdx.x;
  size_t idx = (size_t)row * (DMODEL / 4) + t;
  float4 v = ((const float4*)src)[idx];
  if (MODE >= 1) {
    const size_t slab = (size_t)ROWS * DMODEL / 4;
    float4 p0 = ((const float4*)parts)[idx];
    float4 p1 = ((const float4*)parts)[idx + slab];
    v.x += p0.x + p1.x; v.y += p0.y + p1.y;
    v.z += p0.z + p1.z; v.w += p0.w + p1.w;
  }
  if (MODE <= 1) ((float4*)res_out)[idx] = v;
  float s = v.x + v.y + v.z + v.w;
  float sq = v.x * v.x + v.y * v.y + v.z * v.z + v.w * v.w;
  #pragma unroll
  for (int o = 32; o >= 1; o >>= 1) {
    s += __shfl_xor(s, o);
    sq += __shfl_xor(sq, o);
  }
  __shared__ float ss[4], ssq[4];
  int wid = t >> 6, lane = t & 63;
  if (lane == 0) { ss[wid] = s; ssq[wid] = sq; }
  __syncthreads();
  s = ss[0] + ss[1] + ss[2] + ss[3];
  sq = ssq[0] + ssq[1] + ssq[2] + ssq[3];
  float mu = s * (1.f / DMODEL);
  float var = sq * (1.f / DMODEL) - mu * mu;
  float rs = rsqrtf(var + LNEPS);
  float4 wv = ((const float4*)w)[t];
  float4 bv = ((const float4*)b)[t];
  float4 o4;
  o4.x = (v.x - mu) * rs * wv.x + bv.x;
  o4.y = (v.y - mu) * rs * wv.y + bv.y;
  o4.z = (v.z - mu) * rs * wv.z + bv.z;
  o4.w = (v.w - mu) * rs * wv.w + bv.w;
  if (MODE <= 1) {
    ushort4 ob;
    ob.x = f2bf(o4.x); ob.y = f2bf(o4.y); ob.z = f2bf(o4.z); ob.w = f2bf(o4.w);
    ((ushort4*)out)[idx] = ob;
  } else {
    ((float4*)out)[idx] = o4;
  }
}

// ==== 256x256 bf16 MFMA GEMM, reg-staged + padded LDS (R15-proven, 1-deep) ===
template<int ACT, bool BIAS, bool ADD, bool WF32, bool WBF>
__global__ __launch_bounds__(512) void gemm256r(
    const unsigned short* __restrict__ A, int lda,
    const unsigned short* __restrict__ W, int ldw,
    float* __restrict__ C, int ldc, int K,
    const float* __restrict__ bias,
    const float* __restrict__ addsrc,
    unsigned short* __restrict__ Cb) {
  __shared__ unsigned short lds[2][256][72];   // 72 KB, +16B/row pad
  const int t = threadIdx.x;
  const int lane = t & 63;
  const int wave = t >> 6;
  const int wr = wave >> 2;          // 0..1 (M half)
  const int wc = wave & 3;           // 0..3 (N quarter)
  const int m0 = blockIdx.y * 256, n0 = blockIdx.x * 256;
  const int frow = lane & 15;
  const int hi = lane >> 4;

  const int srow = t >> 3;           // staging row base 0..63 (+64*r)
  const int sc8 = (t & 7) << 3;      // staging chunk col (elements)

  f32x4 acc[8][4];
  #pragma unroll
  for (int m = 0; m < 8; m++)
    #pragma unroll
    for (int n = 0; n < 4; n++) acc[m][n] = (f32x4){0.f, 0.f, 0.f, 0.f};

  const int NT = K / 64;
  ushort8 areg[4], wreg[4];

  auto loadreg = [&](int kt) {
    #pragma unroll
    for (int r = 0; r < 4; ++r) {
      int row = srow + (r << 6);
      areg[r] = *(const ushort8*)(A + (size_t)(m0 + row) * lda + kt * 64 + sc8);
      wreg[r] = *(const ushort8*)(W + (size_t)(n0 + row) * ldw + kt * 64 + sc8);
    }
  };
  auto dswrite = [&]() {
    #pragma unroll
    for (int r = 0; r < 4; ++r) {
      int row = srow + (r << 6);
      *(ushort8*)&lds[0][row][sc8] = areg[r];
      *(ushort8*)&lds[1][row][sc8] = wreg[r];
    }
  };
  auto compute = [&]() {
    #pragma unroll
    for (int ks = 0; ks < 2; ++ks) {
      bf16x8 a[8], b[4];
      #pragma unroll
      for (int m = 0; m < 8; ++m)
        a[m] = *(const bf16x8*)&lds[0][wr * 128 + m * 16 + frow][(ks * 4 + hi) << 3];
      #pragma unroll
      for (int n = 0; n < 4; ++n)
        b[n] = *(const bf16x8*)&lds[1][wc * 64 + n * 16 + frow][(ks * 4 + hi) << 3];
      __builtin_amdgcn_s_setprio(1);
      #pragma unroll
      for (int m = 0; m < 8; ++m)
        #pragma unroll
        for (int n = 0; n < 4; ++n)
          acc[m][n] = __builtin_amdgcn_mfma_f32_16x16x32_bf16(a[m], b[n], acc[m][n], 0, 0, 0);
      __builtin_amdgcn_s_setprio(0);
    }
  };

  loadreg(0);
  dswrite();
  __syncthreads();
  for (int kt = 0; kt < NT; ++kt) {
    if (kt + 1 < NT) loadreg(kt + 1);   // issue early; lands during compute
    compute();
    __syncthreads();                    // all waves done reading this tile
    if (kt + 1 < NT) {
      dswrite();                        // waits on its own loads only
      __syncthreads();                  // writes visible before next compute
    }
  }

  #pragma unroll
  for (int m = 0; m < 8; ++m) {
    int rbase = m0 + wr * 128 + m * 16 + hi * 4;
    #pragma unroll
    for (int n = 0; n < 4; ++n) {
      int ccol = n0 + wc * 64 + n * 16 + frow;
      #pragma unroll
      for (int j = 0; j < 4; ++j) {
        int crow = rbase + j;
        float v = acc[m][n][j];
        if (BIAS) v += bias[ccol];
        if (ACT == 1) v = softplus_f(v);
        if (ADD) v += addsrc[(size_t)crow * ldc + ccol];
        if (WF32) C[(size_t)crow * ldc + ccol] = v;
        if (WBF) Cb[(size_t)crow * ldc + ccol] = f2bf(v);
      }
    }
  }
}

// ------------- 128x128 2-phase GEMM (R12-proven; dt/x/out_proj) --------------
template<int ACT, bool BIAS, bool ADD, bool WF32, bool WBF, bool PARTIAL>
__global__ __launch_bounds__(256) void gemm_bf16(
    const unsigned short* __restrict__ A, int lda,
    const unsigned short* __restrict__ W, int ldw,
    float* __restrict__ C, int ldc, int K,
    const float* __restrict__ bias,
    const float* __restrict__ addsrc,
    unsigned short* __restrict__ Cb) {
  __shared__ unsigned short As[2][128][32];
  __shared__ unsigned short Ws[2][128][32];
  int t = threadIdx.x;
  int lane = t & 63, wave = t >> 6;
  int wr = wave >> 1, wc = wave & 1;
  int m0 = blockIdx.y * 128, n0 = blockIdx.x * 128;

  int kbase = 0;
  if (PARTIAL) {
    kbase = blockIdx.z * K;
    C += (size_t)blockIdx.z * (size_t)gridDim.y * 128 * ldc;
  }

  int r0 = t >> 2;
  int kk8 = (t & 3) << 3;
  const unsigned short* Ag = A + (size_t)(m0 + r0) * lda + kbase + kk8;
  const unsigned short* Wg = W + (size_t)(n0 + r0) * ldw + kbase + kk8;
  const size_t Astep = (size_t)64 * lda;
  const size_t Wstep = (size_t)64 * ldw;

  f32x4 zero = {0.f, 0.f, 0.f, 0.f};
  f32x4 acc[4][4];
  #pragma unroll
  for (int m = 0; m < 4; m++)
    #pragma unroll
    for (int n = 0; n < 4; n++) acc[m][n] = zero;

  int frow = lane & 15;
  int fk = (lane >> 4) << 3;

  auto stage = [&](int buf, int kt) {
    const unsigned short* ag = Ag + kt * 32;
    const unsigned short* wg = Wg + kt * 32;
    unsigned short* la = &As[buf][r0][kk8];
    unsigned short* lw = &Ws[buf][r0][kk8];
    gload16(ag, la);
    gload16(ag + Astep, la + 64 * 32);
    gload16(wg, lw);
    gload16(wg + Wstep, lw + 64 * 32);
  };
  auto compute = [&](int buf) {
    bf16x8 af[4], bw[4];
    #pragma unroll
    for (int m = 0; m < 4; m++)
      af[m] = *(const bf16x8*)&As[buf][wr * 64 + m * 16 + frow][fk];
    #pragma unroll
    for (int n = 0; n < 4; n++)
      bw[n] = *(const bf16x8*)&Ws[buf][wc * 64 + n * 16 + frow][fk];
    #pragma unroll
    for (int m = 0; m < 4; m++)
      #pragma unroll
      for (int n = 0; n < 4; n++)
        acc[m][n] = __builtin_amdgcn_mfma_f32_16x16x32_bf16(af[m], bw[n], acc[m][n], 0, 0, 0);
  };

  const int NT = K / 32;
  stage(0, 0);
  __syncthreads();
  int cur = 0;
  for (int kt = 0; kt < NT - 1; ++kt) {
    stage(cur ^ 1, kt + 1);
    compute(cur);
    __syncthreads();
    cur ^= 1;
  }
  compute(cur);

  #pragma unroll
  for (int m = 0; m < 4; m++) {
    int rbase = m0 + wr * 64 + m * 16 + ((lane >> 4) << 2);
    #pragma unroll
    for (int n = 0; n < 4; n++) {
      int ccol = n0 + wc * 64 + n * 16 + (lane & 15);
      #pragma unroll
      for (int j = 0; j < 4; j++) {
        int crow = rbase + j;
        float v = acc[m][n][j];
        if (BIAS) v += bias[ccol];
        if (ACT == 1) v = softplus_f(v);
        if (ADD) v += addsrc[(size_t)crow * ldc + ccol];
        if (WF32 || PARTIAL) C[(size_t)crow * ldc + ccol] = v;
        if (WBF) Cb[(size_t)crow * ldc + ccol] = f2bf(v);
      }
    }
  }
}

// ---------- split-K combine: xdbl = sum of NSLICE slabs (fp32 + bf16) --------
__global__ __launch_bounds__(256) void combine_xdbl(
    const float* __restrict__ part, float* __restrict__ xdbl,
    unsigned short* __restrict__ xdbl_bf) {
  int i = blockIdx.x * 256 + threadIdx.x;
  const size_t slab = (size_t)ROWS * XP / 4;
  const float4* p = (const float4*)part;
  float4 s = make_float4(0.f, 0.f, 0.f, 0.f);
  #pragma unroll
  for (int z = 0; z < NSLICE; z++) {
    float4 a = p[i + (size_t)z * slab];
    s.x += a.x; s.y += a.y; s.z += a.z; s.w += a.w;
  }
  ((float4*)xdbl)[i] = s;
  ushort4 o;
  o.x = f2bf(s.x); o.y = f2bf(s.y); o.z = f2bf(s.z); o.w = f2bf(s.w);
  ((ushort4*)xdbl_bf)[i] = o;
}

// ------- causal depthwise conv1d + SiLU: 8 ch x 4 rows per thread ------------
__global__ __launch_bounds__(256) void conv_silu_kernel(
    const unsigned short* __restrict__ xz, const float* __restrict__ cw,
    const float* __restrict__ cb, unsigned short* __restrict__ xbf) {
  int tid = blockIdx.x * 256 + threadIdx.x;   // ROWS/4 * DINNER/8 = 262144
  int dv = tid & (DINNER / 8 - 1);
  int rg = tid >> 8;                          // row group (4 rows)
  int l0 = (rg & (LSEQ / 4 - 1)) * 4;         // seq pos of first output row
  int row0 = rg * 4;
  int d = dv * 8;

  float4 wq[8];
  #pragma unroll
  for (int j = 0; j < 8; j++) wq[j] = ((const float4*)(cw + (size_t)d * DCONV))[j];
  float4 b0 = ((const float4*)(cb + d))[0];
  float4 b1 = ((const float4*)(cb + d))[1];
  const float bias[8] = {b0.x, b0.y, b0.z, b0.w, b1.x, b1.y, b1.z, b1.w};

  ushort8 xin[7];
  #pragma unroll
  for (int r = 0; r < 7; r++) {
    int l = l0 - 3 + r;
    if (l >= 0)
      xin[r] = *(const ushort8*)(xz + (size_t)(row0 - 3 + r) * (2 * DINNER) + d);
    else
      xin[r] = (ushort8){0, 0, 0, 0, 0, 0, 0, 0};
  }

  #pragma unroll
  for (int o = 0; o < 4; o++) {
    ushort8 ob;
    #pragma unroll
    for (int j = 0; j < 8; j++) {
      const float* wj = (const float*)&wq[j];
      float acc = bias[j];
      #pragma unroll
      for (int k = 0; k < DCONV; k++)
        acc = fmaf(bf2f(xin[o + k][j]), wj[k], acc);
      float s = acc / (1.f + __expf(-acc));
      ob[j] = f2bf(s);
    }
    *(ushort8*)(xbf + (size_t)(row0 + o) * DINNER + d) = ob;
  }
}

// ==== chunk-parallel selective scan (CLEN=32, LDS B/C, packed bf16 carries,
//      bf16 delta) =============================================================
__global__ __launch_bounds__(256) void scan_p1(
    const unsigned short* __restrict__ delta, const unsigned short* __restrict__ u,
    const float* __restrict__ xdbl, const float* __restrict__ A_log,
    unsigned int* __restrict__ carrybuf) {
  int tid = blockIdx.x * 256 + threadIdx.x;   // B*NCHUNK*DINNER = 131072
  int t = threadIdx.x;
  int d = tid & (DINNER - 1);
  int chunk = (tid >> 11) & (NCHUNK - 1);
  int b = tid >> 17;
  int l0 = chunk * CLEN;

  __shared__ float bl[CLEN][16];              // B rows, 2 KB
  {
    const float4* src4 = (const float4*)(xdbl + ((size_t)b * LSEQ + l0) * XP);
    if (t < CLEN * 4) {
      int li = t >> 2, qi = t & 3;
      ((float4*)&bl[li][0])[qi] = src4[li * (XP / 4) + 16 + qi];
    }
  }
  __syncthreads();

  float A[DSTATE], st[DSTATE], ap[DSTATE];
  const float4* Ar = (const float4*)(A_log + d * DSTATE);
  #pragma unroll
  for (int q = 0; q < 4; q++) {
    float4 av = Ar[q];
    A[4 * q] = -__expf(av.x); A[4 * q + 1] = -__expf(av.y);
    A[4 * q + 2] = -__expf(av.z); A[4 * q + 3] = -__expf(av.w);
  }
  #pragma unroll
  for (int s = 0; s < DSTATE; s++) { st[s] = 0.f; ap[s] = 1.f; }

  const unsigned short* dptr = delta + ((size_t)b * LSEQ + l0) * DINNER + d;
  const unsigned short* uptr = u + ((size_t)b * LSEQ + l0) * DINNER + d;
  float dt_n = bf2f(dptr[0]);
  float uu_n = bf2f(uptr[0]);
  #pragma unroll 4
  for (int l = 0; l < CLEN; l++) {
    float dt = dt_n, uu = uu_n;
    if (l + 1 < CLEN) {
      dt_n = bf2f(dptr[(size_t)(l + 1) * DINNER]);
      uu_n = bf2f(uptr[(size_t)(l + 1) * DINNER]);
    }
    float du = dt * uu;
    #pragma unroll
    for (int q = 0; q < 4; q++) {
      float4 B4 = *(const float4*)&bl[l][q * 4];
      const float Bj[4] = {B4.x, B4.y, B4.z, B4.w};
      #pragma unroll
      for (int j = 0; j < 4; j++) {
        int s = 4 * q + j;
        float dA = __expf(dt * A[s]);
        st[s] = fmaf(dA, st[s], du * Bj[j]);
        ap[s] *= dA;
      }
    }
  }
  uint4v* co = (uint4v*)(carrybuf + (size_t)tid * DSTATE);
  #pragma unroll
  for (int q = 0; q < 4; q++) {
    uint4v v;
    #pragma unroll
    for (int j = 0; j < 4; j++)
      v[j] = ((unsigned int)f2bf(ap[4 * q + j]) << 16) | f2bf(st[4 * q + j]);
    co[q] = v;
  }
}

// P2: sequential combine over NCHUNK packed chunks; fp32 carry accumulation.
__global__ __launch_bounds__(256) void scan_p2(
    const unsigned int* __restrict__ cbuf, unsigned short* __restrict__ carryin) {
  int tid = blockIdx.x * 256 + threadIdx.x;   // B*DINNER*DSTATE = 65536
  int ds = tid & (DINNER * DSTATE - 1);
  int b = tid >> 15;
  float carry = 0.f;
  size_t base = (size_t)b * NCHUNK * DINNER * DSTATE + ds;
  const size_t cs = DINNER * DSTATE;
  for (int c = 0; c < NCHUNK; c += 4) {
    size_t i0 = base + (size_t)c * cs;
    unsigned int v0 = cbuf[i0], v1 = cbuf[i0 + cs];
    unsigned int v2 = cbuf[i0 + 2 * cs], v3 = cbuf[i0 + 3 * cs];
    carryin[i0] = f2bf(carry);
    carry = fmaf(bf2f(v0 >> 16), carry, bf2f(v0 & 0xFFFFu));
    carryin[i0 + cs] = f2bf(carry);
    carry = fmaf(bf2f(v1 >> 16), carry, bf2f(v1 & 0xFFFFu));
    carryin[i0 + 2 * cs] = f2bf(carry);
    carry = fmaf(bf2f(v2 >> 16), carry, bf2f(v2 & 0xFFFFu));
    carryin[i0 + 3 * cs] = f2bf(carry);
    carry = fmaf(bf2f(v3 >> 16), carry, bf2f(v3 & 0xFFFFu));
  }
}

// P3: seeded re-scan + y = (C.state + u*D) * silu(z); B/C from LDS.
__global__ __launch_bounds__(256) void scan_p3(
    const unsigned short* __restrict__ delta, const unsigned short* __restrict__ u,
    const float* __restrict__ xdbl, const unsigned short* __restrict__ xzbf,
    const float* __restrict__ A_log, const float* __restrict__ Dp,
    const unsigned short* __restrict__ carryin, unsigned short* __restrict__ ybf) {
  int tid = blockIdx.x * 256 + threadIdx.x;
  int t = threadIdx.x;
  int d = tid & (DINNER - 1);
  int chunk = (tid >> 11) & (NCHUNK - 1);
  int b = tid >> 17;
  int l0 = chunk * CLEN;

  __shared__ float bc[CLEN][32];              // B+C rows, 4 KB
  {
    const float4* src4 = (const float4*)(xdbl + ((size_t)b * LSEQ + l0) * XP);
    int li = t >> 3, qi = t & 7;              // 256 threads = 32 rows x 8 quads
    ((float4*)&bc[li][0])[qi] = src4[li * (XP / 4) + 16 + qi];
  }
  __syncthreads();

  float A[DSTATE], st[DSTATE];
  {
    const ushort8* ci8 = (const ushort8*)(carryin + (size_t)tid * DSTATE);
    ushort8 c0 = ci8[0], c1 = ci8[1];
    #pragma unroll
    for (int j = 0; j < 8; j++) { st[j] = bf2f(c0[j]); st[8 + j] = bf2f(c1[j]); }
  }
  const float4* Ar = (const float4*)(A_log + d * DSTATE);
  #pragma unroll
  for (int q = 0; q < 4; q++) {
    float4 av = Ar[q];
    A[4 * q] = -__expf(av.x); A[4 * q + 1] = -__expf(av.y);
    A[4 * q + 2] = -__expf(av.z); A[4 * q + 3] = -__expf(av.w);
  }
  float Dval = Dp[d];

  const unsigned short* dptr = delta + ((size_t)b * LSEQ + l0) * DINNER + d;
  const unsigned short* uptr = u + ((size_t)b * LSEQ + l0) * DINNER + d;
  const unsigned short* zptr = xzbf + ((size_t)b * LSEQ + l0) * (2 * DINNER) + DINNER + d;
  unsigned short* yptr = ybf + ((size_t)b * LSEQ + l0) * DINNER + d;

  float dt_n = bf2f(dptr[0]);
  float uu_n = bf2f(uptr[0]);
  float zz_n = bf2f(zptr[0]);
  #pragma unroll 4
  for (int l = 0; l < CLEN; l++) {
    float dt = dt_n, uu = uu_n, zz = zz_n;
    if (l + 1 < CLEN) {
      dt_n = bf2f(dptr[(size_t)(l + 1) * DINNER]);
      uu_n = bf2f(uptr[(size_t)(l + 1) * DINNER]);
      zz_n = bf2f(zptr[(size_t)(l + 1) * (2 * DINNER)]);
    }
    float du = dt * uu;
    #pragma unroll
    for (int q = 0; q < 4; q++) {
      float4 B4 = *(const float4*)&bc[l][q * 4];
      const float Bj[4] = {B4.x, B4.y, B4.z, B4.w};
      #pragma unroll
      for (int j = 0; j < 4; j++) {
        int s = 4 * q + j;
        float dA = __expf(dt * A[s]);
        st[s] = fmaf(dA, st[s], du * Bj[j]);
      }
    }
    float acc = 0.f;
    #pragma unroll
    for (int q = 0; q < 4; q++) {
      float4 C4 = *(const float4*)&bc[l][16 + q * 4];
      const float Cj[4] = {C4.x, C4.y, C4.z, C4.w};
      #pragma unroll
      for (int j = 0; j < 4; j++) acc = fmaf(st[4 * q + j], Cj[j], acc);
    }
    float yv = (acc + uu * Dval) * (zz / (1.f + __expf(-zz)));
    yptr[(size_t)l * DINNER] = f2bf(yv);
  }
}

extern "C" void kernel_launch(void* const* d_in, const int* in_sizes, int n_in,
                              void* d_out, int out_size, void* d_ws, size_t ws_size,
                              hipStream_t stream) {
  const float* hidden    = (const float*)d_in[0];
  const float* norm_w    = (const float*)d_in[1];
  const float* norm_b    = (const float*)d_in[2];
  const float* in_proj_w = (const float*)d_in[3];
  const float* conv_w    = (const float*)d_in[4];
  const float* conv_b    = (const float*)d_in[5];
  const float* x_proj_w  = (const float*)d_in[6];
  const float* dt_proj_w = (const float*)d_in[7];
  const float* dt_proj_b = (const float*)d_in[8];
  const float* A_log     = (const float*)d_in[9];
  const float* Dp        = (const float*)d_in[10];
  const float* out_proj_w= (const float*)d_in[11];
  const float* fnw       = (const float*)d_in[12];
  const float* fnb       = (const float*)d_in[13];
  float* out = (float*)d_out;

  const size_t CARRYSZ = (size_t)NBATCH * NCHUNK * DINNER * DSTATE;  // 4M entries

  // ---- workspace layout (≈150 MiB; 209.5 proven safe) ----
  float* residual = (float*)d_ws;                                   // 16 MiB
  float* dregion  = residual + (size_t)ROWS * DMODEL;               // 32 MiB multi-use
  float* xdbl     = dregion + (size_t)ROWS * DINNER;                // 2 MiB
  float* fend     = xdbl + (size_t)ROWS * XP;

  unsigned short* xz_bf   = (unsigned short*)fend;                        // 32 MiB
  unsigned short* xbuf_bf = xz_bf + (size_t)ROWS * 2 * DINNER;            // 16 MiB
  unsigned short* h_bf    = xbuf_bf + (size_t)ROWS * DINNER;              // 8 MiB
  unsigned short* ybuf_bf = h_bf + (size_t)ROWS * DMODEL;                 // 16 MiB
  unsigned short* xdbl_bf = ybuf_bf + (size_t)ROWS * DINNER;              // 1 MiB
  unsigned short* xpw_bf  = xdbl_bf + (size_t)ROWS * XP;                  // 2 MiB
  unsigned short* dtw_bf  = xpw_bf + (size_t)N_LAYERS * XP * DINNER;      // 1 MiB
  unsigned short* ipw_bf  = dtw_bf + (size_t)N_LAYERS * DINNER * DTRANK;  // 8 MiB (per layer)
  unsigned short* opw_bf  = ipw_bf + (size_t)2 * DINNER * DMODEL;         // 4 MiB (per layer)
  unsigned short* usend   = opw_bf + (size_t)DMODEL * DINNER;

  unsigned int*   carrybuf = (unsigned int*)usend;                        // 16 MiB
  unsigned short* carryin  = (unsigned short*)(carrybuf + CARRYSZ);       // 8 MiB
  // dregion multi-use (lifetime-disjoint, stream-ordered):
  //   x_proj partials (16 MiB) -> dt_proj writes delta_bf (8 MiB) ->
  //   p1/p3 read delta_bf -> out_proj partials (32 MiB) -> next LN consumes
  float*          xpart    = dregion;
  unsigned short* delta_bf = (unsigned short*)dregion;
  float*          oppart   = dregion;

  // one-time small weight conversions
  cvt_xpw<<<N_LAYERS * XP * DINNER / 4 / 256, 256, 0, stream>>>(x_proj_w, xpw_bf);
  {
    int n4 = N_LAYERS * DINNER * DTRANK / 4;
    cvt_f2bf<<<n4 / 256, 256, 0, stream>>>(dt_proj_w, dtw_bf, n4);
  }

  for (int i = 0; i < N_LAYERS; i++) {
    {
      int n4 = 2 * DINNER * DMODEL / 4;
      cvt_f2bf<<<n4 / 256, 256, 0, stream>>>(
          in_proj_w + (size_t)i * 2 * DINNER * DMODEL, ipw_bf, n4);
      n4 = DMODEL * DINNER / 4;
      cvt_f2bf<<<n4 / 256, 256, 0, stream>>>(
          out_proj_w + (size_t)i * DMODEL * DINNER, opw_bf, n4);
    }
    // LN (fused with previous layer's out_proj combine for i>0)
    if (i == 0)
      ln_kernel<0><<<ROWS, 256, 0, stream>>>(
          hidden, nullptr, norm_w, norm_b, h_bf, residual);
    else
      ln_kernel<1><<<ROWS, 256, 0, stream>>>(
          residual, oppart, norm_w + (size_t)i * DMODEL,
          norm_b + (size_t)i * DMODEL, h_bf, residual);
    // in_proj -> xz bf16   (256x256 reg-staged, grid 16x16)
    {
      dim3 g(2 * DINNER / 256, ROWS / 256);
      gemm256r<0, false, false, false, true><<<g, 512, 0, stream>>>(
          h_bf, DMODEL, ipw_bf, DMODEL, nullptr, 2 * DINNER, DMODEL,
          nullptr, nullptr, xz_bf);
    }
    conv_silu_kernel<<<ROWS / 4 * DINNER / 8 / 256, 256, 0, stream>>>(
        xz_bf, conv_w + (size_t)i * DINNER * DCONV, conv_b + (size_t)i * DINNER,
        xbuf_bf);
    // x_proj: split-K (8 x K=256, 256 blocks) -> partials, then combine
    {
      dim3 g(1, ROWS / 128, NSLICE);
      gemm_bf16<0, false, false, true, false, true><<<g, 256, 0, stream>>>(
          xbuf_bf, DINNER, xpw_bf + (size_t)i * XP * DINNER, DINNER,
          xpart, XP, KSLICE, nullptr, nullptr, nullptr);
      combine_xdbl<<<ROWS * XP / 4 / 256, 256, 0, stream>>>(xpart, xdbl, xdbl_bf);
    }
    // dt_proj + bias + softplus -> delta bf16  (128x128, grid 16x32)
    {
      dim3 g(DINNER / 128, ROWS / 128);
      gemm_bf16<1, true, false, false, true, false><<<g, 256, 0, stream>>>(
          xdbl_bf, XP, dtw_bf + (size_t)i * DINNER * DTRANK, DTRANK,
          nullptr, DINNER, DTRANK, dt_proj_b + (size_t)i * DINNER,
          nullptr, delta_bf);
    }
    // chunk-parallel scan
    scan_p1<<<NBATCH * NCHUNK * DINNER / 256, 256, 0, stream>>>(
        delta_bf, xbuf_bf, xdbl, A_log + (size_t)i * DINNER * DSTATE, carrybuf);
    scan_p2<<<NBATCH * DINNER * DSTATE / 256, 256, 0, stream>>>(carrybuf, carryin);
    scan_p3<<<NBATCH * NCHUNK * DINNER / 256, 256, 0, stream>>>(
        delta_bf, xbuf_bf, xdbl, xz_bf, A_log + (size_t)i * DINNER * DSTATE,
        Dp + (size_t)i * DINNER, carryin, ybuf_bf);
    // out_proj: split-K (2 x K=1024, 512 blocks = 2/CU) -> partials in dregion;
    // consumed by the NEXT LayerNorm (fused combine)
    {
      dim3 g(DMODEL / 128, ROWS / 128, OPSLICE);
      gemm_bf16<0, false, false, false, false, true><<<g, 256, 0, stream>>>(
          ybuf_bf, DINNER, opw_bf, DINNER,
          oppart, DMODEL, DINNER / OPSLICE, nullptr, nullptr, nullptr);
    }
  }
  // final LN with fused combine of layer-3's out_proj partials
  ln_kernel<2><<<ROWS, 256, 0, stream>>>(residual, oppart, fnw, fnb, out, nullptr);
}

// Round 19
// 860.661 us; speedup vs baseline: 1.4550x; 1.0095x over previous
//
#include <hip/hip_runtime.h>
#include <math.h>

#define N_LAYERS 4
#define DMODEL 1024
#define DINNER 2048
#define DSTATE 16
#define DTRANK 64
#define DCONV 4
#define NBATCH 2
#define LSEQ 2048
#define LNEPS 1e-5f
#define ROWS (NBATCH * LSEQ)   // 4096
#define CLEN 32
#define NCHUNK (LSEQ / CLEN)   // 64
#define XP 128                 // padded x_proj output pitch (dt 0:64, B 64:80, C 80:96)
#define KSLICE 256             // x_proj split-K slice
#define NSLICE (DINNER / KSLICE)  // 8
#define OPSLICE 2              // out_proj split-K slices

typedef __attribute__((ext_vector_type(8))) short bf16x8;
typedef __attribute__((ext_vector_type(8))) unsigned short ushort8;
typedef __attribute__((ext_vector_type(4))) float f32x4;
typedef __attribute__((ext_vector_type(4))) unsigned int uint4v;

__device__ __forceinline__ unsigned short f2bf(float f) {
  unsigned int u = __float_as_uint(f);
  return (unsigned short)((u + 0x7FFFu + ((u >> 16) & 1u)) >> 16);  // RNE
}
__device__ __forceinline__ float bf2f(unsigned short h) {
  return __uint_as_float(((unsigned int)h) << 16);
}

__device__ __forceinline__ void gload16(const unsigned short* g, unsigned short* l) {
  __builtin_amdgcn_global_load_lds(
      (const __attribute__((address_space(1))) unsigned int*)g,
      (__attribute__((address_space(3))) unsigned int*)l, 16, 0, 0);
}

// fast softplus via HW v_exp/v_log (R7: libm version cost 100 us/layer)
__device__ __forceinline__ float softplus_f(float x) {
  float e = __expf(-fabsf(x));
  return fmaxf(x, 0.f) + __logf(1.f + e);
}

// ---------------- fp32 -> bf16 weight conversion -----------------------------
__global__ __launch_bounds__(256) void cvt_f2bf(const float* __restrict__ src,
                                                unsigned short* __restrict__ dst, int n4) {
  int i = blockIdx.x * 256 + threadIdx.x;
  if (i >= n4) return;
  float4 v = ((const float4*)src)[i];
  ushort4 o;
  o.x = f2bf(v.x); o.y = f2bf(v.y); o.z = f2bf(v.z); o.w = f2bf(v.w);
  ((ushort4*)dst)[i] = o;
}

// x_proj_w [4][96][2048] -> padded bf16 [4][128][2048] (rows 96..127 zero)
__global__ __launch_bounds__(256) void cvt_xpw(const float* __restrict__ src,
                                               unsigned short* __restrict__ dst) {
  int i = blockIdx.x * 256 + threadIdx.x;    // over 4*128*512
  int col4 = i & 511;
  int row = (i >> 9) & 127;
  int layer = i >> 16;
  float4 v = make_float4(0.f, 0.f, 0.f, 0.f);
  if (row < 96) v = ((const float4*)(src + ((size_t)layer * 96 + row) * 2048))[col4];
  ushort4 o;
  o.x = f2bf(v.x); o.y = f2bf(v.y); o.z = f2bf(v.z); o.w = f2bf(v.w);
  ((ushort4*)(dst + ((size_t)layer * 128 + row) * 2048))[col4] = o;
}

// ---- LayerNorm with fused out_proj split-K combine (R18) --------------------
// MODE 0: v = src            ; residual <- v ; bf16 LN out   (layer 0)
// MODE 1: v = src + p0 + p1  ; residual <- v ; bf16 LN out   (layers 1..3)
// MODE 2: v = src + p0 + p1  ;                 fp32 LN out   (final)
template<int MODE>
__global__ __launch_bounds__(256) void ln_kernel(
    const float* __restrict__ src, const float* __restrict__ parts,
    const float* __restrict__ w, const float* __restrict__ b,
    void* out, float* __restrict__ res_out) {
  int row = blockIdx.x;
  int t = threadIdx.x;
  size_t idx = (size_t)row * (DMODEL / 4) + t;
  float4 v = ((const float4*)src)[idx];
  if (MODE >= 1) {
    const size_t slab = (size_t)ROWS * DMODEL / 4;
    float4 p0 = ((const float4*)parts)[idx];
    float4 p1 = ((const float4*)parts)[idx + slab];
    v.x += p0.x + p1.x; v.y += p0.y + p1.y;
    v.z += p0.z + p1.z; v.w += p0.w + p1.w;
  }
  if (MODE <= 1) ((float4*)res_out)[idx] = v;
  float s = v.x + v.y + v.z + v.w;
  float sq = v.x * v.x + v.y * v.y + v.z * v.z + v.w * v.w;
  #pragma unroll
  for (int o = 32; o >= 1; o >>= 1) {
    s += __shfl_xor(s, o);
    sq += __shfl_xor(sq, o);
  }
  __shared__ float ss[4], ssq[4];
  int wid = t >> 6, lane = t & 63;
  if (lane == 0) { ss[wid] = s; ssq[wid] = sq; }
  __syncthreads();
  s = ss[0] + ss[1] + ss[2] + ss[3];
  sq = ssq[0] + ssq[1] + ssq[2] + ssq[3];
  float mu = s * (1.f / DMODEL);
  float var = sq * (1.f / DMODEL) - mu * mu;
  float rs = rsqrtf(var + LNEPS);
  float4 wv = ((const float4*)w)[t];
  float4 bv = ((const float4*)b)[t];
  float4 o4;
  o4.x = (v.x - mu) * rs * wv.x + bv.x;
  o4.y = (v.y - mu) * rs * wv.y + bv.y;
  o4.z = (v.z - mu) * rs * wv.z + bv.z;
  o4.w = (v.w - mu) * rs * wv.w + bv.w;
  if (MODE <= 1) {
    ushort4 ob;
    ob.x = f2bf(o4.x); ob.y = f2bf(o4.y); ob.z = f2bf(o4.z); ob.w = f2bf(o4.w);
    ((ushort4*)out)[idx] = ob;
  } else {
    ((float4*)out)[idx] = o4;
  }
}

// ==== 256x256 bf16 MFMA GEMM, reg-staged + padded LDS (R15-proven, 1-deep) ===
template<int ACT, bool BIAS, bool ADD, bool WF32, bool WBF>
__global__ __launch_bounds__(512) void gemm256r(
    const unsigned short* __restrict__ A, int lda,
    const unsigned short* __restrict__ W, int ldw,
    float* __restrict__ C, int ldc, int K,
    const float* __restrict__ bias,
    const float* __restrict__ addsrc,
    unsigned short* __restrict__ Cb) {
  __shared__ unsigned short lds[2][256][72];   // 72 KB, +16B/row pad
  const int t = threadIdx.x;
  const int lane = t & 63;
  const int wave = t >> 6;
  const int wr = wave >> 2;          // 0..1 (M half)
  const int wc = wave & 3;           // 0..3 (N quarter)
  const int m0 = blockIdx.y * 256, n0 = blockIdx.x * 256;
  const int frow = lane & 15;
  const int hi = lane >> 4;

  const int srow = t >> 3;           // staging row base 0..63 (+64*r)
  const int sc8 = (t & 7) << 3;      // staging chunk col (elements)

  f32x4 acc[8][4];
  #pragma unroll
  for (int m = 0; m < 8; m++)
    #pragma unroll
    for (int n = 0; n < 4; n++) acc[m][n] = (f32x4){0.f, 0.f, 0.f, 0.f};

  const int NT = K / 64;
  ushort8 areg[4], wreg[4];

  auto loadreg = [&](int kt) {
    #pragma unroll
    for (int r = 0; r < 4; ++r) {
      int row = srow + (r << 6);
      areg[r] = *(const ushort8*)(A + (size_t)(m0 + row) * lda + kt * 64 + sc8);
      wreg[r] = *(const ushort8*)(W + (size_t)(n0 + row) * ldw + kt * 64 + sc8);
    }
  };
  auto dswrite = [&]() {
    #pragma unroll
    for (int r = 0; r < 4; ++r) {
      int row = srow + (r << 6);
      *(ushort8*)&lds[0][row][sc8] = areg[r];
      *(ushort8*)&lds[1][row][sc8] = wreg[r];
    }
  };
  auto compute = [&]() {
    #pragma unroll
    for (int ks = 0; ks < 2; ++ks) {
      bf16x8 a[8], b[4];
      #pragma unroll
      for (int m = 0; m < 8; ++m)
        a[m] = *(const bf16x8*)&lds[0][wr * 128 + m * 16 + frow][(ks * 4 + hi) << 3];
      #pragma unroll
      for (int n = 0; n < 4; ++n)
        b[n] = *(const bf16x8*)&lds[1][wc * 64 + n * 16 + frow][(ks * 4 + hi) << 3];
      __builtin_amdgcn_s_setprio(1);
      #pragma unroll
      for (int m = 0; m < 8; ++m)
        #pragma unroll
        for (int n = 0; n < 4; ++n)
          acc[m][n] = __builtin_amdgcn_mfma_f32_16x16x32_bf16(a[m], b[n], acc[m][n], 0, 0, 0);
      __builtin_amdgcn_s_setprio(0);
    }
  };

  loadreg(0);
  dswrite();
  __syncthreads();
  for (int kt = 0; kt < NT; ++kt) {
    if (kt + 1 < NT) loadreg(kt + 1);   // issue early; lands during compute
    compute();
    __syncthreads();                    // all waves done reading this tile
    if (kt + 1 < NT) {
      dswrite();                        // waits on its own loads only
      __syncthreads();                  // writes visible before next compute
    }
  }

  #pragma unroll
  for (int m = 0; m < 8; ++m) {
    int rbase = m0 + wr * 128 + m * 16 + hi * 4;
    #pragma unroll
    for (int n = 0; n < 4; ++n) {
      int ccol = n0 + wc * 64 + n * 16 + frow;
      #pragma unroll
      for (int j = 0; j < 4; ++j) {
        int crow = rbase + j;
        float v = acc[m][n][j];
        if (BIAS) v += bias[ccol];
        if (ACT == 1) v = softplus_f(v);
        if (ADD) v += addsrc[(size_t)crow * ldc + ccol];
        if (WF32) C[(size_t)crow * ldc + ccol] = v;
        if (WBF) Cb[(size_t)crow * ldc + ccol] = f2bf(v);
      }
    }
  }
}

// ------------- 128x128 2-phase GEMM (R12-proven; dt/x/out_proj) --------------
template<int ACT, bool BIAS, bool ADD, bool WF32, bool WBF, bool PARTIAL>
__global__ __launch_bounds__(256) void gemm_bf16(
    const unsigned short* __restrict__ A, int lda,
    const unsigned short* __restrict__ W, int ldw,
    float* __restrict__ C, int ldc, int K,
    const float* __restrict__ bias,
    const float* __restrict__ addsrc,
    unsigned short* __restrict__ Cb) {
  __shared__ unsigned short As[2][128][32];
  __shared__ unsigned short Ws[2][128][32];
  int t = threadIdx.x;
  int lane = t & 63, wave = t >> 6;
  int wr = wave >> 1, wc = wave & 1;
  int m0 = blockIdx.y * 128, n0 = blockIdx.x * 128;

  int kbase = 0;
  if (PARTIAL) {
    kbase = blockIdx.z * K;
    C += (size_t)blockIdx.z * (size_t)gridDim.y * 128 * ldc;
  }

  int r0 = t >> 2;
  int kk8 = (t & 3) << 3;
  const unsigned short* Ag = A + (size_t)(m0 + r0) * lda + kbase + kk8;
  const unsigned short* Wg = W + (size_t)(n0 + r0) * ldw + kbase + kk8;
  const size_t Astep = (size_t)64 * lda;
  const size_t Wstep = (size_t)64 * ldw;

  f32x4 zero = {0.f, 0.f, 0.f, 0.f};
  f32x4 acc[4][4];
  #pragma unroll
  for (int m = 0; m < 4; m++)
    #pragma unroll
    for (int n = 0; n < 4; n++) acc[m][n] = zero;

  int frow = lane & 15;
  int fk = (lane >> 4) << 3;

  auto stage = [&](int buf, int kt) {
    const unsigned short* ag = Ag + kt * 32;
    const unsigned short* wg = Wg + kt * 32;
    unsigned short* la = &As[buf][r0][kk8];
    unsigned short* lw = &Ws[buf][r0][kk8];
    gload16(ag, la);
    gload16(ag + Astep, la + 64 * 32);
    gload16(wg, lw);
    gload16(wg + Wstep, lw + 64 * 32);
  };
  auto compute = [&](int buf) {
    bf16x8 af[4], bw[4];
    #pragma unroll
    for (int m = 0; m < 4; m++)
      af[m] = *(const bf16x8*)&As[buf][wr * 64 + m * 16 + frow][fk];
    #pragma unroll
    for (int n = 0; n < 4; n++)
      bw[n] = *(const bf16x8*)&Ws[buf][wc * 64 + n * 16 + frow][fk];
    #pragma unroll
    for (int m = 0; m < 4; m++)
      #pragma unroll
      for (int n = 0; n < 4; n++)
        acc[m][n] = __builtin_amdgcn_mfma_f32_16x16x32_bf16(af[m], bw[n], acc[m][n], 0, 0, 0);
  };

  const int NT = K / 32;
  stage(0, 0);
  __syncthreads();
  int cur = 0;
  for (int kt = 0; kt < NT - 1; ++kt) {
    stage(cur ^ 1, kt + 1);
    compute(cur);
    __syncthreads();
    cur ^= 1;
  }
  compute(cur);

  #pragma unroll
  for (int m = 0; m < 4; m++) {
    int rbase = m0 + wr * 64 + m * 16 + ((lane >> 4) << 2);
    #pragma unroll
    for (int n = 0; n < 4; n++) {
      int ccol = n0 + wc * 64 + n * 16 + (lane & 15);
      #pragma unroll
      for (int j = 0; j < 4; j++) {
        int crow = rbase + j;
        float v = acc[m][n][j];
        if (BIAS) v += bias[ccol];
        if (ACT == 1) v = softplus_f(v);
        if (ADD) v += addsrc[(size_t)crow * ldc + ccol];
        if (WF32 || PARTIAL) C[(size_t)crow * ldc + ccol] = v;
        if (WBF) Cb[(size_t)crow * ldc + ccol] = f2bf(v);
      }
    }
  }
}

// ---------- split-K combine: xdbl = sum of NSLICE slabs (fp32 + bf16) --------
__global__ __launch_bounds__(256) void combine_xdbl(
    const float* __restrict__ part, float* __restrict__ xdbl,
    unsigned short* __restrict__ xdbl_bf) {
  int i = blockIdx.x * 256 + threadIdx.x;
  const size_t slab = (size_t)ROWS * XP / 4;
  const float4* p = (const float4*)part;
  float4 s = make_float4(0.f, 0.f, 0.f, 0.f);
  #pragma unroll
  for (int z = 0; z < NSLICE; z++) {
    float4 a = p[i + (size_t)z * slab];
    s.x += a.x; s.y += a.y; s.z += a.z; s.w += a.w;
  }
  ((float4*)xdbl)[i] = s;
  ushort4 o;
  o.x = f2bf(s.x); o.y = f2bf(s.y); o.z = f2bf(s.z); o.w = f2bf(s.w);
  ((ushort4*)xdbl_bf)[i] = o;
}

// ------- causal depthwise conv1d + SiLU: 8 ch x 4 rows per thread ------------
__global__ __launch_bounds__(256) void conv_silu_kernel(
    const unsigned short* __restrict__ xz, const float* __restrict__ cw,
    const float* __restrict__ cb, unsigned short* __restrict__ xbf) {
  int tid = blockIdx.x * 256 + threadIdx.x;   // ROWS/4 * DINNER/8 = 262144
  int dv = tid & (DINNER / 8 - 1);
  int rg = tid >> 8;                          // row group (4 rows)
  int l0 = (rg & (LSEQ / 4 - 1)) * 4;         // seq pos of first output row
  int row0 = rg * 4;
  int d = dv * 8;

  float4 wq[8];
  #pragma unroll
  for (int j = 0; j < 8; j++) wq[j] = ((const float4*)(cw + (size_t)d * DCONV))[j];
  float4 b0 = ((const float4*)(cb + d))[0];
  float4 b1 = ((const float4*)(cb + d))[1];
  const float bias[8] = {b0.x, b0.y, b0.z, b0.w, b1.x, b1.y, b1.z, b1.w};

  ushort8 xin[7];
  #pragma unroll
  for (int r = 0; r < 7; r++) {
    int l = l0 - 3 + r;
    if (l >= 0)
      xin[r] = *(const ushort8*)(xz + (size_t)(row0 - 3 + r) * (2 * DINNER) + d);
    else
      xin[r] = (ushort8){0, 0, 0, 0, 0, 0, 0, 0};
  }

  #pragma unroll
  for (int o = 0; o < 4; o++) {
    ushort8 ob;
    #pragma unroll
    for (int j = 0; j < 8; j++) {
      const float* wj = (const float*)&wq[j];
      float acc = bias[j];
      #pragma unroll
      for (int k = 0; k < DCONV; k++)
        acc = fmaf(bf2f(xin[o + k][j]), wj[k], acc);
      float s = acc / (1.f + __expf(-acc));
      ob[j] = f2bf(s);
    }
    *(ushort8*)(xbf + (size_t)(row0 + o) * DINNER + d) = ob;
  }
}

// ==== chunk-parallel selective scan (CLEN=32, LDS B/C, packed bf16 carries,
//      bf16 delta) =============================================================
__global__ __launch_bounds__(256) void scan_p1(
    const unsigned short* __restrict__ delta, const unsigned short* __restrict__ u,
    const float* __restrict__ xdbl, const float* __restrict__ A_log,
    unsigned int* __restrict__ carrybuf) {
  int tid = blockIdx.x * 256 + threadIdx.x;   // B*NCHUNK*DINNER = 131072
  int t = threadIdx.x;
  int d = tid & (DINNER - 1);
  int chunk = (tid >> 11) & (NCHUNK - 1);
  int b = tid >> 17;
  int l0 = chunk * CLEN;

  __shared__ float bl[CLEN][16];              // B rows, 2 KB
  {
    const float4* src4 = (const float4*)(xdbl + ((size_t)b * LSEQ + l0) * XP);
    if (t < CLEN * 4) {
      int li = t >> 2, qi = t & 3;
      ((float4*)&bl[li][0])[qi] = src4[li * (XP / 4) + 16 + qi];
    }
  }
  __syncthreads();

  float A[DSTATE], st[DSTATE], ap[DSTATE];
  const float4* Ar = (const float4*)(A_log + d * DSTATE);
  #pragma unroll
  for (int q = 0; q < 4; q++) {
    float4 av = Ar[q];
    A[4 * q] = -__expf(av.x); A[4 * q + 1] = -__expf(av.y);
    A[4 * q + 2] = -__expf(av.z); A[4 * q + 3] = -__expf(av.w);
  }
  #pragma unroll
  for (int s = 0; s < DSTATE; s++) { st[s] = 0.f; ap[s] = 1.f; }

  const unsigned short* dptr = delta + ((size_t)b * LSEQ + l0) * DINNER + d;
  const unsigned short* uptr = u + ((size_t)b * LSEQ + l0) * DINNER + d;
  float dt_n = bf2f(dptr[0]);
  float uu_n = bf2f(uptr[0]);
  #pragma unroll 4
  for (int l = 0; l < CLEN; l++) {
    float dt = dt_n, uu = uu_n;
    if (l + 1 < CLEN) {
      dt_n = bf2f(dptr[(size_t)(l + 1) * DINNER]);
      uu_n = bf2f(uptr[(size_t)(l + 1) * DINNER]);
    }
    float du = dt * uu;
    #pragma unroll
    for (int q = 0; q < 4; q++) {
      float4 B4 = *(const float4*)&bl[l][q * 4];
      const float Bj[4] = {B4.x, B4.y, B4.z, B4.w};
      #pragma unroll
      for (int j = 0; j < 4; j++) {
        int s = 4 * q + j;
        float dA = __expf(dt * A[s]);
        st[s] = fmaf(dA, st[s], du * Bj[j]);
        ap[s] *= dA;
      }
    }
  }
  uint4v* co = (uint4v*)(carrybuf + (size_t)tid * DSTATE);
  #pragma unroll
  for (int q = 0; q < 4; q++) {
    uint4v v;
    #pragma unroll
    for (int j = 0; j < 4; j++)
      v[j] = ((unsigned int)f2bf(ap[4 * q + j]) << 16) | f2bf(st[4 * q + j]);
    co[q] = v;
  }
}

// P2: sequential combine over NCHUNK packed chunks; fp32 carry accumulation.
__global__ __launch_bounds__(256) void scan_p2(
    const unsigned int* __restrict__ cbuf, unsigned short* __restrict__ carryin) {
  int tid = blockIdx.x * 256 + threadIdx.x;   // B*DINNER*DSTATE = 65536
  int ds = tid & (DINNER * DSTATE - 1);
  int b = tid >> 15;
  float carry = 0.f;
  size_t base = (size_t)b * NCHUNK * DINNER * DSTATE + ds;
  const size_t cs = DINNER * DSTATE;
  for (int c = 0; c < NCHUNK; c += 4) {
    size_t i0 = base + (size_t)c * cs;
    unsigned int v0 = cbuf[i0], v1 = cbuf[i0 + cs];
    unsigned int v2 = cbuf[i0 + 2 * cs], v3 = cbuf[i0 + 3 * cs];
    carryin[i0] = f2bf(carry);
    carry = fmaf(bf2f(v0 >> 16), carry, bf2f(v0 & 0xFFFFu));
    carryin[i0 + cs] = f2bf(carry);
    carry = fmaf(bf2f(v1 >> 16), carry, bf2f(v1 & 0xFFFFu));
    carryin[i0 + 2 * cs] = f2bf(carry);
    carry = fmaf(bf2f(v2 >> 16), carry, bf2f(v2 & 0xFFFFu));
    carryin[i0 + 3 * cs] = f2bf(carry);
    carry = fmaf(bf2f(v3 >> 16), carry, bf2f(v3 & 0xFFFFu));
  }
}

// P3: seeded re-scan + y = (C.state + u*D) * silu(z); B/C from LDS.
__global__ __launch_bounds__(256) void scan_p3(
    const unsigned short* __restrict__ delta, const unsigned short* __restrict__ u,
    const float* __restrict__ xdbl, const unsigned short* __restrict__ xzbf,
    const float* __restrict__ A_log, const float* __restrict__ Dp,
    const unsigned short* __restrict__ carryin, unsigned short* __restrict__ ybf) {
  int tid = blockIdx.x * 256 + threadIdx.x;
  int t = threadIdx.x;
  int d = tid & (DINNER - 1);
  int chunk = (tid >> 11) & (NCHUNK - 1);
  int b = tid >> 17;
  int l0 = chunk * CLEN;

  __shared__ float bc[CLEN][32];              // B+C rows, 4 KB
  {
    const float4* src4 = (const float4*)(xdbl + ((size_t)b * LSEQ + l0) * XP);
    int li = t >> 3, qi = t & 7;              // 256 threads = 32 rows x 8 quads
    ((float4*)&bc[li][0])[qi] = src4[li * (XP / 4) + 16 + qi];
  }
  __syncthreads();

  float A[DSTATE], st[DSTATE];
  {
    const ushort8* ci8 = (const ushort8*)(carryin + (size_t)tid * DSTATE);
    ushort8 c0 = ci8[0], c1 = ci8[1];
    #pragma unroll
    for (int j = 0; j < 8; j++) { st[j] = bf2f(c0[j]); st[8 + j] = bf2f(c1[j]); }
  }
  const float4* Ar = (const float4*)(A_log + d * DSTATE);
  #pragma unroll
  for (int q = 0; q < 4; q++) {
    float4 av = Ar[q];
    A[4 * q] = -__expf(av.x); A[4 * q + 1] = -__expf(av.y);
    A[4 * q + 2] = -__expf(av.z); A[4 * q + 3] = -__expf(av.w);
  }
  float Dval = Dp[d];

  const unsigned short* dptr = delta + ((size_t)b * LSEQ + l0) * DINNER + d;
  const unsigned short* uptr = u + ((size_t)b * LSEQ + l0) * DINNER + d;
  const unsigned short* zptr = xzbf + ((size_t)b * LSEQ + l0) * (2 * DINNER) + DINNER + d;
  unsigned short* yptr = ybf + ((size_t)b * LSEQ + l0) * DINNER + d;

  float dt_n = bf2f(dptr[0]);
  float uu_n = bf2f(uptr[0]);
  float zz_n = bf2f(zptr[0]);
  #pragma unroll 4
  for (int l = 0; l < CLEN; l++) {
    float dt = dt_n, uu = uu_n, zz = zz_n;
    if (l + 1 < CLEN) {
      dt_n = bf2f(dptr[(size_t)(l + 1) * DINNER]);
      uu_n = bf2f(uptr[(size_t)(l + 1) * DINNER]);
      zz_n = bf2f(zptr[(size_t)(l + 1) * (2 * DINNER)]);
    }
    float du = dt * uu;
    #pragma unroll
    for (int q = 0; q < 4; q++) {
      float4 B4 = *(const float4*)&bc[l][q * 4];
      const float Bj[4] = {B4.x, B4.y, B4.z, B4.w};
      #pragma unroll
      for (int j = 0; j < 4; j++) {
        int s = 4 * q + j;
        float dA = __expf(dt * A[s]);
        st[s] = fmaf(dA, st[s], du * Bj[j]);
      }
    }
    float acc = 0.f;
    #pragma unroll
    for (int q = 0; q < 4; q++) {
      float4 C4 = *(const float4*)&bc[l][16 + q * 4];
      const float Cj[4] = {C4.x, C4.y, C4.z, C4.w};
      #pragma unroll
      for (int j = 0; j < 4; j++) acc = fmaf(st[4 * q + j], Cj[j], acc);
    }
    float yv = (acc + uu * Dval) * (zz / (1.f + __expf(-zz)));
    yptr[(size_t)l * DINNER] = f2bf(yv);
  }
}

extern "C" void kernel_launch(void* const* d_in, const int* in_sizes, int n_in,
                              void* d_out, int out_size, void* d_ws, size_t ws_size,
                              hipStream_t stream) {
  const float* hidden    = (const float*)d_in[0];
  const float* norm_w    = (const float*)d_in[1];
  const float* norm_b    = (const float*)d_in[2];
  const float* in_proj_w = (const float*)d_in[3];
  const float* conv_w    = (const float*)d_in[4];
  const float* conv_b    = (const float*)d_in[5];
  const float* x_proj_w  = (const float*)d_in[6];
  const float* dt_proj_w = (const float*)d_in[7];
  const float* dt_proj_b = (const float*)d_in[8];
  const float* A_log     = (const float*)d_in[9];
  const float* Dp        = (const float*)d_in[10];
  const float* out_proj_w= (const float*)d_in[11];
  const float* fnw       = (const float*)d_in[12];
  const float* fnb       = (const float*)d_in[13];
  float* out = (float*)d_out;

  const size_t CARRYSZ = (size_t)NBATCH * NCHUNK * DINNER * DSTATE;  // 4M entries

  // ---- workspace layout (≈198 MiB; 209.5 proven safe in R2) ----
  float* residual = (float*)d_ws;                                   // 16 MiB
  float* dregion  = residual + (size_t)ROWS * DMODEL;               // 32 MiB multi-use
  float* xdbl     = dregion + (size_t)ROWS * DINNER;                // 2 MiB
  float* fend     = xdbl + (size_t)ROWS * XP;

  unsigned short* xz_bf   = (unsigned short*)fend;                        // 32 MiB
  unsigned short* xbuf_bf = xz_bf + (size_t)ROWS * 2 * DINNER;            // 16 MiB
  unsigned short* h_bf    = xbuf_bf + (size_t)ROWS * DINNER;              // 8 MiB
  unsigned short* ybuf_bf = h_bf + (size_t)ROWS * DMODEL;                 // 16 MiB
  unsigned short* xdbl_bf = ybuf_bf + (size_t)ROWS * DINNER;              // 1 MiB
  unsigned short* xpw_bf  = xdbl_bf + (size_t)ROWS * XP;                  // 2 MiB (all layers)
  unsigned short* dtw_bf  = xpw_bf + (size_t)N_LAYERS * XP * DINNER;      // 1 MiB (all layers)
  unsigned short* ipw_bf  = dtw_bf + (size_t)N_LAYERS * DINNER * DTRANK;  // 32 MiB (all layers)
  unsigned short* opw_bf  = ipw_bf + (size_t)N_LAYERS * 2 * DINNER * DMODEL; // 16 MiB (all layers)
  unsigned short* usend   = opw_bf + (size_t)N_LAYERS * DMODEL * DINNER;

  unsigned int*   carrybuf = (unsigned int*)usend;                        // 16 MiB
  unsigned short* carryin  = (unsigned short*)(carrybuf + CARRYSZ);       // 8 MiB
  // dregion multi-use (lifetime-disjoint, stream-ordered):
  //   x_proj partials (16 MiB) -> dt_proj writes delta_bf (8 MiB) ->
  //   p1/p3 read delta_bf -> out_proj partials (32 MiB) -> next LN consumes
  float*          xpart    = dregion;
  unsigned short* delta_bf = (unsigned short*)dregion;
  float*          oppart   = dregion;

  // one-time weight conversions (ALL layers, hoisted out of the loop — R19)
  cvt_xpw<<<N_LAYERS * XP * DINNER / 4 / 256, 256, 0, stream>>>(x_proj_w, xpw_bf);
  {
    int n4 = N_LAYERS * DINNER * DTRANK / 4;
    cvt_f2bf<<<n4 / 256, 256, 0, stream>>>(dt_proj_w, dtw_bf, n4);
    n4 = N_LAYERS * 2 * DINNER * DMODEL / 4;
    cvt_f2bf<<<n4 / 256, 256, 0, stream>>>(in_proj_w, ipw_bf, n4);
    n4 = N_LAYERS * DMODEL * DINNER / 4;
    cvt_f2bf<<<n4 / 256, 256, 0, stream>>>(out_proj_w, opw_bf, n4);
  }

  for (int i = 0; i < N_LAYERS; i++) {
    // LN (fused with previous layer's out_proj combine for i>0)
    if (i == 0)
      ln_kernel<0><<<ROWS, 256, 0, stream>>>(
          hidden, nullptr, norm_w, norm_b, h_bf, residual);
    else
      ln_kernel<1><<<ROWS, 256, 0, stream>>>(
          residual, oppart, norm_w + (size_t)i * DMODEL,
          norm_b + (size_t)i * DMODEL, h_bf, residual);
    // in_proj -> xz bf16   (256x256 reg-staged, grid 16x16)
    {
      dim3 g(2 * DINNER / 256, ROWS / 256);
      gemm256r<0, false, false, false, true><<<g, 512, 0, stream>>>(
          h_bf, DMODEL, ipw_bf + (size_t)i * 2 * DINNER * DMODEL, DMODEL,
          nullptr, 2 * DINNER, DMODEL, nullptr, nullptr, xz_bf);
    }
    conv_silu_kernel<<<ROWS / 4 * DINNER / 8 / 256, 256, 0, stream>>>(
        xz_bf, conv_w + (size_t)i * DINNER * DCONV, conv_b + (size_t)i * DINNER,
        xbuf_bf);
    // x_proj: split-K (8 x K=256, 256 blocks) -> partials, then combine
    {
      dim3 g(1, ROWS / 128, NSLICE);
      gemm_bf16<0, false, false, true, false, true><<<g, 256, 0, stream>>>(
          xbuf_bf, DINNER, xpw_bf + (size_t)i * XP * DINNER, DINNER,
          xpart, XP, KSLICE, nullptr, nullptr, nullptr);
      combine_xdbl<<<ROWS * XP / 4 / 256, 256, 0, stream>>>(xpart, xdbl, xdbl_bf);
    }
    // dt_proj + bias + softplus -> delta bf16  (128x128, grid 16x32)
    {
      dim3 g(DINNER / 128, ROWS / 128);
      gemm_bf16<1, true, false, false, true, false><<<g, 256, 0, stream>>>(
          xdbl_bf, XP, dtw_bf + (size_t)i * DINNER * DTRANK, DTRANK,
          nullptr, DINNER, DTRANK, dt_proj_b + (size_t)i * DINNER,
          nullptr, delta_bf);
    }
    // chunk-parallel scan
    scan_p1<<<NBATCH * NCHUNK * DINNER / 256, 256, 0, stream>>>(
        delta_bf, xbuf_bf, xdbl, A_log + (size_t)i * DINNER * DSTATE, carrybuf);
    scan_p2<<<NBATCH * DINNER * DSTATE / 256, 256, 0, stream>>>(carrybuf, carryin);
    scan_p3<<<NBATCH * NCHUNK * DINNER / 256, 256, 0, stream>>>(
        delta_bf, xbuf_bf, xdbl, xz_bf, A_log + (size_t)i * DINNER * DSTATE,
        Dp + (size_t)i * DINNER, carryin, ybuf_bf);
    // out_proj: split-K (2 x K=1024, 512 blocks = 2/CU) -> partials in dregion;
    // consumed by the NEXT LayerNorm (fused combine)
    {
      dim3 g(DMODEL / 128, ROWS / 128, OPSLICE);
      gemm_bf16<0, false, false, false, false, true><<<g, 256, 0, stream>>>(
          ybuf_bf, DINNER, opw_bf + (size_t)i * DMODEL * DINNER, DINNER,
          oppart, DMODEL, DINNER / OPSLICE, nullptr, nullptr, nullptr);
    }
  }
  // final LN with fused combine of layer-3's out_proj partials
  ln_kernel<2><<<ROWS, 256, 0, stream>>>(residual, oppart, fnw, fnb, out, nullptr);
}